// Round 14
// baseline (1059.009 us; speedup 1.0000x reference)
//
#include <hip/hip_runtime.h>
#include <hip/hip_bf16.h>
#include <stdint.h>

// ---------------------------------------------------------------------------
// Packed 2xfp32 helpers — lower to v_pk_fma_f32 / v_pk_add_f32 / v_pk_max_f32
// ---------------------------------------------------------------------------
typedef float f32x2 __attribute__((ext_vector_type(2)));

__device__ __forceinline__ f32x2 mk2(float a, float b) { f32x2 r; r.x = a; r.y = b; return r; }
__device__ __forceinline__ f32x2 bc2(float a) { f32x2 r; r.x = a; r.y = a; return r; }
__device__ __forceinline__ f32x2 max2(f32x2 a, f32x2 b) {
#if __has_builtin(__builtin_elementwise_max)
    return __builtin_elementwise_max(a, b);
#else
    return mk2(fmaxf(a.x, b.x), fmaxf(a.y, b.y));
#endif
}
__device__ __forceinline__ f32x2 min2(f32x2 a, f32x2 b) {
#if __has_builtin(__builtin_elementwise_min)
    return __builtin_elementwise_min(a, b);
#else
    return mk2(fminf(a.x, b.x), fminf(a.y, b.y));
#endif
}

// ---------------------------------------------------------------------------
// DPP helpers: reductions within each 16-lane row (VALU pipe, no LDS traffic)
// ---------------------------------------------------------------------------
template <int CTRL>
__device__ __forceinline__ float dppmov(float v) {
    return __int_as_float(__builtin_amdgcn_update_dpp(
        0, __float_as_int(v), CTRL, 0xF, 0xF, true));
}
__device__ __forceinline__ float grp_sum16(float v) {
    v += dppmov<0xB1>(v);   // quad_perm xor1
    v += dppmov<0x4E>(v);   // quad_perm xor2
    v += dppmov<0x124>(v);  // row_ror:4
    v += dppmov<0x128>(v);  // row_ror:8
    return v;
}
__device__ __forceinline__ float grp_max16(float v) {
    v = fmaxf(v, dppmov<0xB1>(v));
    v = fmaxf(v, dppmov<0x4E>(v));
    v = fmaxf(v, dppmov<0x124>(v));
    v = fmaxf(v, dppmov<0x128>(v));
    return v;
}

// ---------------------------------------------------------------------------
// fp32 tiled GEMM, inner loop packed (8 pk_fma vs 16 fma per k-step)
// ---------------------------------------------------------------------------
#define TM 64
#define TN 64
#define TK 16

__global__ __launch_bounds__(256) void gemm_tiled(
    const float* __restrict__ A, int lda,
    const float* __restrict__ B, int ldb,
    float* __restrict__ C, int ldc,
    int M, int N, int kc, const float* __restrict__ bias)
{
    __shared__ float As[TK][TM + 4];
    __shared__ float Bs[TK][TN + 4];
    const int tid = threadIdx.x;
    const int bm = blockIdx.y * TM;
    const int bn = blockIdx.x * TN;
    const int k0 = blockIdx.z * kc;
    C += (size_t)blockIdx.z * M * N;

    const int tx = tid & 15;
    const int ty = tid >> 4;

    f32x2 acc[4][2];
#pragma unroll
    for (int i = 0; i < 4; ++i) {
        if (bias) {
            acc[i][0] = mk2(bias[bn + tx * 4 + 0], bias[bn + tx * 4 + 1]);
            acc[i][1] = mk2(bias[bn + tx * 4 + 2], bias[bn + tx * 4 + 3]);
        } else {
            acc[i][0] = bc2(0.0f);
            acc[i][1] = bc2(0.0f);
        }
    }

    const int ar = tid >> 2;
    const int ac = (tid & 3) * 4;
    const int br = tid >> 4;
    const int bc = (tid & 15) * 4;

    for (int kt = k0; kt < k0 + kc; kt += TK) {
        float4 a = *(const float4*)&A[(size_t)(bm + ar) * lda + kt + ac];
        float4 b = *(const float4*)&B[(size_t)(kt + br) * ldb + bn + bc];
        As[ac + 0][ar] = a.x; As[ac + 1][ar] = a.y;
        As[ac + 2][ar] = a.z; As[ac + 3][ar] = a.w;
        *(float4*)&Bs[br][bc] = b;
        __syncthreads();
#pragma unroll
        for (int kk = 0; kk < TK; ++kk) {
            float4 a4 = *(const float4*)&As[kk][ty * 4];
            float4 b4 = *(const float4*)&Bs[kk][tx * 4];
            f32x2 b01 = mk2(b4.x, b4.y), b23 = mk2(b4.z, b4.w);
            float av[4] = {a4.x, a4.y, a4.z, a4.w};
#pragma unroll
            for (int i = 0; i < 4; ++i) {
                f32x2 ai = bc2(av[i]);
                acc[i][0] = ai * b01 + acc[i][0];   // v_pk_fma_f32
                acc[i][1] = ai * b23 + acc[i][1];
            }
        }
        __syncthreads();
    }
#pragma unroll
    for (int i = 0; i < 4; ++i) {
        float4 o = make_float4(acc[i][0].x, acc[i][0].y, acc[i][1].x, acc[i][1].y);
        *(float4*)&C[(size_t)(bm + ty * 4 + i) * ldc + bn + tx * 4] = o;
    }
}

// ---------------------------------------------------------------------------
// Fused per-half-token attn, round 13 = round-12 (packed 2-rows-per-group)
// with the residual scratch spill removed: scores/PV loops FULLY unrolled so
// every xa[]/xb[] index is a compile-time constant (SROA-guaranteed register
// promotion, rule-20), and launch bound relaxed to (256,2) so the ~110-reg
// live set fits without pressure spill. WRITE_SIZE==8192 is the tripwire.
// ---------------------------------------------------------------------------
#define NSOLVE 4
#define NBISECT 3
#define NNEWTON 6

__global__ __launch_bounds__(256, 2) void attn_entmax(
    const float* qg, const float* kg, const float* vg,
    float* resg, const float* __restrict__ alpha_p)
{
    __shared__ float ks[8 * 512];
    __shared__ float vs[8 * 512];
    __shared__ float qs[8 * 256];
    const int t = blockIdx.x >> 1;
    const int base = (blockIdx.x & 1) << 8;    // row half: 0 or 256
    const int tid = threadIdx.x;

    const float alpha = alpha_p[0];
    const float expo = 1.0f / (alpha - 1.0f);      // = 2 for alpha=1.5 (exact)
    const bool fast = (expo == 2.0f);
    const float scl = (alpha - 1.0f) * 0.04419417382415922f;  // (a-1)/sqrt(512)
    const float hispan = powf(1.0f / 512.0f, alpha - 1.0f);   // m - tau_hi

    {   // stage K, V (full token) and q (this block's 256 rows)
        const float4* k4 = (const float4*)(kg + (size_t)t * 4096);
        const float4* v4 = (const float4*)(vg + (size_t)t * 4096);
#pragma unroll
        for (int u = 0; u < 4; ++u) {
            int idx = tid + 256 * u;
            ((float4*)ks)[idx] = k4[idx];
            ((float4*)vs)[idx] = v4[idx];
        }
        const float4* q4 = (const float4*)(qg + (size_t)t * 4096);
#pragma unroll
        for (int u = 0; u < 2; ++u) {
            int idx = tid + 256 * u;               // = h*64 + j4
            ((float4*)qs)[idx] = q4[(idx >> 6) * 128 + (base >> 2) + (idx & 63)];
        }
    }
    __syncthreads();

    const int lane = tid & 63;
    const int w = tid >> 6;        // wave 0..3
    const int sub = lane >> 4;     // 16-lane group 0..3
    const int lx = lane & 15;

    const f32x2 zero2 = bc2(0.0f);
    const f32x2 one2  = bc2(1.0f);
    const f32x2 big2  = bc2(1e30f);
    const f32x2 scl2  = bc2(scl);

    for (int it = 0; it < 8; ++it) {
        const int il0 = it * 32 + w * 4 + sub;   // this group's row pair
        const int il1 = il0 + 16;

        float qv0[8], qv1[8];
#pragma unroll
        for (int h = 0; h < 8; ++h) {
            qv0[h] = qs[h * 256 + il0];
            qv1[h] = qs[h * 256 + il1];
        }

        // ---- scores for BOTH rows; lane cols j = lx*4 + 64*u + {0..3}
        f32x2 xa[16], xb[16];
        f32x2 mva = bc2(-1e30f), sva = zero2;
        f32x2 mvb = bc2(-1e30f), svb = zero2;
#pragma unroll
        for (int u = 0; u < 8; ++u) {
            f32x2 A0 = zero2, B0 = zero2, A1 = zero2, B1 = zero2;
#pragma unroll
            for (int h = 0; h < 8; ++h) {
                float4 k4 = *(const float4*)&ks[h * 512 + lx * 4 + 64 * u];
                f32x2 k01 = mk2(k4.x, k4.y), k23 = mk2(k4.z, k4.w);
                f32x2 q0 = bc2(qv0[h]), q1 = bc2(qv1[h]);
                A0 = q0 * k01 + A0; B0 = q0 * k23 + B0;
                A1 = q1 * k01 + A1; B1 = q1 * k23 + B1;
            }
            A0 = A0 * scl2; B0 = B0 * scl2;
            A1 = A1 * scl2; B1 = B1 * scl2;
            xa[2 * u] = A0; xa[2 * u + 1] = B0;
            xb[2 * u] = A1; xb[2 * u + 1] = B1;
            mva = max2(mva, max2(A0, B0)); sva = sva + A0 + B0;
            mvb = max2(mvb, max2(A1, B1)); svb = svb + A1 + B1;
        }
        const float m0 = grp_max16(fmaxf(mva.x, mva.y));
        const float m1 = grp_max16(fmaxf(mvb.x, mvb.y));
        const float tlo0 = m0 - 1.0f, thi0 = m0 - hispan;
        const float tlo1 = m1 - 1.0f, thi1 = m1 - hispan;

        float tau0, tau1;
        if (fast) {
            float sa0 = grp_sum16(sva.x + sva.y);
            float sa1 = grp_sum16(svb.x + svb.y);
            tau0 = fminf(fmaxf(sa0 * (1.0f / 512.0f), tlo0), thi0);
            tau1 = fminf(fmaxf(sa1 * (1.0f / 512.0f), tlo1), thi1);
#pragma unroll
            for (int itr = 0; itr < NSOLVE; ++itr) {
                f32x2 t20 = bc2(tau0), t21 = bc2(tau1);
                f32x2 s1A0 = zero2, s2A0 = zero2, cA0 = zero2;
                f32x2 s1A1 = zero2, s2A1 = zero2, cA1 = zero2;
#pragma unroll
                for (int j = 0; j < 16; ++j) {
                    f32x2 rp0 = max2(xa[j] - t20, zero2);
                    f32x2 rp1 = max2(xb[j] - t21, zero2);
                    s1A0 = s1A0 + rp0;
                    s1A1 = s1A1 + rp1;
                    s2A0 = rp0 * rp0 + s2A0;
                    s2A1 = rp1 * rp1 + s2A1;
                    cA0 = cA0 + min2(rp0 * big2, one2);
                    cA1 = cA1 + min2(rp1 * big2, one2);
                }
                float s10 = grp_sum16(s1A0.x + s1A0.y);
                float s20 = grp_sum16(s2A0.x + s2A0.y);
                float n0  = grp_sum16(cA0.x + cA0.y);
                float s11 = grp_sum16(s1A1.x + s1A1.y);
                float s21 = grp_sum16(s2A1.x + s2A1.y);
                float n1  = grp_sum16(cA1.x + cA1.y);
                float d0 = fmaxf(fmaf(s10, s10, -n0 * (s20 - 1.0f)), 0.0f);
                float d1 = fmaxf(fmaf(s11, s11, -n1 * (s21 - 1.0f)), 0.0f);
                tau0 += (s10 - sqrtf(d0)) / fmaxf(n0, 1.0f);
                tau1 += (s11 - sqrtf(d1)) / fmaxf(n1, 1.0f);
                tau0 = fminf(fmaxf(tau0, tlo0), thi0);
                tau1 = fminf(fmaxf(tau1, tlo1), thi1);
            }
        } else {
            // generic alpha: bisect + Newton (powf path), both rows
            tau0 = tlo0; tau1 = tlo1;
            float dm = 1.0f - hispan;
#pragma unroll
            for (int bi = 0; bi < NBISECT; ++bi) {
                dm *= 0.5f;
                float tm0 = tau0 + dm, tm1 = tau1 + dm;
                float f0 = 0.0f, f1 = 0.0f;
#pragma unroll
                for (int j = 0; j < 16; ++j) {
                    f0 += __powf(fmaxf(xa[j].x - tm0, 0.0f), expo);
                    f0 += __powf(fmaxf(xa[j].y - tm0, 0.0f), expo);
                    f1 += __powf(fmaxf(xb[j].x - tm1, 0.0f), expo);
                    f1 += __powf(fmaxf(xb[j].y - tm1, 0.0f), expo);
                }
                f0 = grp_sum16(f0);
                f1 = grp_sum16(f1);
                if (f0 >= 1.0f) tau0 = tm0;
                if (f1 >= 1.0f) tau1 = tm1;
            }
#pragma unroll
            for (int ni = 0; ni < NNEWTON; ++ni) {
                float f0 = 0, g0 = 0, f1 = 0, g1 = 0;
#pragma unroll
                for (int j = 0; j < 16; ++j) {
                    float r0x = fmaxf(xa[j].x - tau0, 0.0f);
                    float p0x = __powf(r0x, expo - 1.0f);
                    g0 += p0x; f0 += p0x * r0x;
                    float r0y = fmaxf(xa[j].y - tau0, 0.0f);
                    float p0y = __powf(r0y, expo - 1.0f);
                    g0 += p0y; f0 += p0y * r0y;
                    float r1x = fmaxf(xb[j].x - tau1, 0.0f);
                    float p1x = __powf(r1x, expo - 1.0f);
                    g1 += p1x; f1 += p1x * r1x;
                    float r1y = fmaxf(xb[j].y - tau1, 0.0f);
                    float p1y = __powf(r1y, expo - 1.0f);
                    g1 += p1y; f1 += p1y * r1y;
                }
                f0 = grp_sum16(f0); g0 = grp_sum16(g0);
                f1 = grp_sum16(f1); g1 = grp_sum16(g1);
                tau0 += (f0 - 1.0f) / fmaxf(expo * g0, 1e-30f);
                tau1 += (f1 - 1.0f) / fmaxf(expo * g1, 1e-30f);
                tau0 = fminf(fmaxf(tau0, tlo0), thi0);
                tau1 = fminf(fmaxf(tau1, tlo1), thi1);
            }
        }

        // ---- final p (unnormalized) back into xa/xb; S packed
        float S0, S1;
        if (fast) {
            f32x2 t20 = bc2(tau0), t21 = bc2(tau1);
            f32x2 SA0 = zero2, SA1 = zero2;
#pragma unroll
            for (int j = 0; j < 16; ++j) {
                f32x2 r0 = max2(xa[j] - t20, zero2);
                f32x2 r1 = max2(xb[j] - t21, zero2);
                f32x2 p0 = r0 * r0, p1 = r1 * r1;
                xa[j] = p0; xb[j] = p1;
                SA0 = SA0 + p0; SA1 = SA1 + p1;
            }
            S0 = SA0.x + SA0.y;
            S1 = SA1.x + SA1.y;
        } else {
            float s0 = 0.0f, s1 = 0.0f;
#pragma unroll
            for (int j = 0; j < 16; ++j) {
                float p0x = __powf(fmaxf(xa[j].x - tau0, 0.0f), expo);
                float p0y = __powf(fmaxf(xa[j].y - tau0, 0.0f), expo);
                float p1x = __powf(fmaxf(xb[j].x - tau1, 0.0f), expo);
                float p1y = __powf(fmaxf(xb[j].y - tau1, 0.0f), expo);
                xa[j] = mk2(p0x, p0y); xb[j] = mk2(p1x, p1y);
                s0 += p0x + p0y; s1 += p1x + p1y;
            }
            S0 = s0; S1 = s1;
        }
        S0 = grp_sum16(S0);
        S1 = grp_sum16(S1);
        const float iS0 = 1.0f / S0, iS1 = 1.0f / S1;

        // ---- res[h,i] = invS * sum_j p[j] v[h,j]; V reads shared by 2 rows
#pragma unroll
        for (int h = 0; h < 8; ++h) {
            f32x2 aA0 = zero2, aB0 = zero2, aA1 = zero2, aB1 = zero2;
#pragma unroll
            for (int u = 0; u < 8; ++u) {
                float4 v4 = *(const float4*)&vs[h * 512 + lx * 4 + 64 * u];
                f32x2 v01 = mk2(v4.x, v4.y), v23 = mk2(v4.z, v4.w);
                aA0 = xa[2 * u] * v01 + aA0;
                aB0 = xa[2 * u + 1] * v23 + aB0;
                aA1 = xb[2 * u] * v01 + aA1;
                aB1 = xb[2 * u + 1] * v23 + aB1;
            }
            float a0 = (aA0.x + aA0.y) + (aB0.x + aB0.y);
            float a1 = (aA1.x + aA1.y) + (aB1.x + aB1.y);
            a0 = grp_sum16(a0) * iS0;
            a1 = grp_sum16(a1) * iS1;
            if (lx == h) {
                resg[(size_t)t * 4096 + h * 512 + base + il0] = a0;
                resg[(size_t)t * 4096 + h * 512 + base + il1] = a1;
            }
        }
    }
}

// ---------------------------------------------------------------------------
__global__ __launch_bounds__(256) void reduce_bias(
    const float* __restrict__ part, const float* __restrict__ bu,
    float* __restrict__ out, int MN, int S)
{
    int i = blockIdx.x * 256 + threadIdx.x;
    if (i >= MN) return;
    float a = bu[i & 511];
#pragma unroll
    for (int s = 0; s < 8; ++s) a += part[(size_t)s * MN + i];
    out[i] = a;
}

// ---------------------------------------------------------------------------
extern "C" void kernel_launch(void* const* d_in, const int* in_sizes, int n_in,
                              void* d_out, int out_size, void* d_ws, size_t ws_size,
                              hipStream_t stream)
{
    const float* x  = (const float*)d_in[0];
    const float* Wq = (const float*)d_in[1];
    const float* bq = (const float*)d_in[2];
    const float* Wk = (const float*)d_in[3];
    const float* bk = (const float*)d_in[4];
    const float* Wv = (const float*)d_in[5];
    const float* bv = (const float*)d_in[6];
    const float* Wu = (const float*)d_in[7];
    const float* bu = (const float*)d_in[8];
    const float* al = (const float*)d_in[9];
    float* out = (float*)d_out;
    float* ws = (float*)d_ws;

    // ws layout (floats): q[2M] | k[2M] | v[2M]
    // res aliases q (disjoint per-block row slices); split-K partials alias k.
    float* q = ws;
    float* k = ws + 2097152;
    float* v = ws + 2 * 2097152;
    float* res = q;
    float* part = k;

    dim3 blk(256);

    dim3 g1(4096 / TN, 512 / TM, 1);
    gemm_tiled<<<g1, blk, 0, stream>>>(x, 512, Wq, 4096, q, 4096, 512, 4096, 512, bq);
    gemm_tiled<<<g1, blk, 0, stream>>>(x, 512, Wk, 4096, k, 4096, 512, 4096, 512, bk);
    gemm_tiled<<<g1, blk, 0, stream>>>(x, 512, Wv, 4096, v, 4096, 512, 4096, 512, bv);

    // fused scores + alpha-entmax + P*V^T, half token per block
    attn_entmax<<<dim3(1024), blk, 0, stream>>>(q, k, v, res, al);

    dim3 g3(512 / TN, 512 / TM, 8);
    gemm_tiled<<<g3, blk, 0, stream>>>(res, 4096, Wu, 512, part, 512, 512, 512, 512, nullptr);
    reduce_bias<<<dim3(262144 / 256), blk, 0, stream>>>(part, bu, out, 262144, 8);
}

// Round 15
// 361.101 us; speedup vs baseline: 2.9327x; 2.9327x over previous
//
#include <hip/hip_runtime.h>
#include <hip/hip_bf16.h>
#include <stdint.h>

// ---------------------------------------------------------------------------
// Packed 2xfp32 helpers — lower to v_pk_fma_f32 / v_pk_add_f32 / v_pk_max_f32
// ---------------------------------------------------------------------------
typedef float f32x2 __attribute__((ext_vector_type(2)));

__device__ __forceinline__ f32x2 mk2(float a, float b) { f32x2 r; r.x = a; r.y = b; return r; }
__device__ __forceinline__ f32x2 bc2(float a) { f32x2 r; r.x = a; r.y = a; return r; }
__device__ __forceinline__ f32x2 max2(f32x2 a, f32x2 b) {
#if __has_builtin(__builtin_elementwise_max)
    return __builtin_elementwise_max(a, b);
#else
    return mk2(fmaxf(a.x, b.x), fmaxf(a.y, b.y));
#endif
}
__device__ __forceinline__ f32x2 min2(f32x2 a, f32x2 b) {
#if __has_builtin(__builtin_elementwise_min)
    return __builtin_elementwise_min(a, b);
#else
    return mk2(fminf(a.x, b.x), fminf(a.y, b.y));
#endif
}

// ---------------------------------------------------------------------------
// DPP helpers: reductions within each 16-lane row (VALU pipe, no LDS traffic)
// ---------------------------------------------------------------------------
template <int CTRL>
__device__ __forceinline__ float dppmov(float v) {
    return __int_as_float(__builtin_amdgcn_update_dpp(
        0, __float_as_int(v), CTRL, 0xF, 0xF, true));
}
__device__ __forceinline__ float grp_sum16(float v) {
    v += dppmov<0xB1>(v);   // quad_perm xor1
    v += dppmov<0x4E>(v);   // quad_perm xor2
    v += dppmov<0x124>(v);  // row_ror:4
    v += dppmov<0x128>(v);  // row_ror:8
    return v;
}
__device__ __forceinline__ float grp_max16(float v) {
    v = fmaxf(v, dppmov<0xB1>(v));
    v = fmaxf(v, dppmov<0x4E>(v));
    v = fmaxf(v, dppmov<0x124>(v));
    v = fmaxf(v, dppmov<0x128>(v));
    return v;
}

// ---------------------------------------------------------------------------
// fp32 tiled GEMM, inner loop packed (8 pk_fma vs 16 fma per k-step)
// ---------------------------------------------------------------------------
#define TM 64
#define TN 64
#define TK 16

__global__ __launch_bounds__(256) void gemm_tiled(
    const float* __restrict__ A, int lda,
    const float* __restrict__ B, int ldb,
    float* __restrict__ C, int ldc,
    int M, int N, int kc, const float* __restrict__ bias)
{
    __shared__ float As[TK][TM + 4];
    __shared__ float Bs[TK][TN + 4];
    const int tid = threadIdx.x;
    const int bm = blockIdx.y * TM;
    const int bn = blockIdx.x * TN;
    const int k0 = blockIdx.z * kc;
    C += (size_t)blockIdx.z * M * N;

    const int tx = tid & 15;
    const int ty = tid >> 4;

    f32x2 acc[4][2];
#pragma unroll
    for (int i = 0; i < 4; ++i) {
        if (bias) {
            acc[i][0] = mk2(bias[bn + tx * 4 + 0], bias[bn + tx * 4 + 1]);
            acc[i][1] = mk2(bias[bn + tx * 4 + 2], bias[bn + tx * 4 + 3]);
        } else {
            acc[i][0] = bc2(0.0f);
            acc[i][1] = bc2(0.0f);
        }
    }

    const int ar = tid >> 2;
    const int ac = (tid & 3) * 4;
    const int br = tid >> 4;
    const int bc = (tid & 15) * 4;

    for (int kt = k0; kt < k0 + kc; kt += TK) {
        float4 a = *(const float4*)&A[(size_t)(bm + ar) * lda + kt + ac];
        float4 b = *(const float4*)&B[(size_t)(kt + br) * ldb + bn + bc];
        As[ac + 0][ar] = a.x; As[ac + 1][ar] = a.y;
        As[ac + 2][ar] = a.z; As[ac + 3][ar] = a.w;
        *(float4*)&Bs[br][bc] = b;
        __syncthreads();
#pragma unroll
        for (int kk = 0; kk < TK; ++kk) {
            float4 a4 = *(const float4*)&As[kk][ty * 4];
            float4 b4 = *(const float4*)&Bs[kk][tx * 4];
            f32x2 b01 = mk2(b4.x, b4.y), b23 = mk2(b4.z, b4.w);
            float av[4] = {a4.x, a4.y, a4.z, a4.w};
#pragma unroll
            for (int i = 0; i < 4; ++i) {
                f32x2 ai = bc2(av[i]);
                acc[i][0] = ai * b01 + acc[i][0];   // v_pk_fma_f32
                acc[i][1] = ai * b23 + acc[i][1];
            }
        }
        __syncthreads();
    }
#pragma unroll
    for (int i = 0; i < 4; ++i) {
        float4 o = make_float4(acc[i][0].x, acc[i][0].y, acc[i][1].x, acc[i][1].y);
        *(float4*)&C[(size_t)(bm + ty * 4 + i) * ldc + bn + tx * 4] = o;
    }
}

// ---------------------------------------------------------------------------
// Fused quarter-token attn, round 14 = round-11 register core VERBATIM
// (single x2[16], one row per 16-lane group, #pragma unroll 2 — the ONLY
// pattern hipcc reliably SROAs; r12 dual-array and r13 full-unroll both
// spilled). Changes vs r11: (1) q read directly from global per row
// (L2-resident broadcast), pre-scaled -> qs LDS buffer deleted, LDS 40->32KB
// -> 5 blocks/CU; (2) quarter-token blocks, grid 2048 (r8-proven mapping)
// -> occupancy ~50-60%; (3) NSOLVE 4->3 (exact solve converges in <=3 from
// the mean seed). WRITE_SIZE == 8192 is the no-scratch tripwire.
// ---------------------------------------------------------------------------
#define QROWS 128
#define NSOLVE 3
#define NBISECT 3
#define NNEWTON 6

__global__ __launch_bounds__(256, 4) void attn_entmax(
    const float* __restrict__ qg, const float* __restrict__ kg,
    const float* __restrict__ vg, float* resg,
    const float* __restrict__ alpha_p)
{
    __shared__ float ks[8 * 512];
    __shared__ float vs[8 * 512];
    const int t = blockIdx.x >> 2;
    const int base = (blockIdx.x & 3) * QROWS;
    const int tid = threadIdx.x;

    const float alpha = alpha_p[0];
    const float expo = 1.0f / (alpha - 1.0f);      // = 2 for alpha=1.5 (exact)
    const bool fast = (expo == 2.0f);
    const float scl = (alpha - 1.0f) * 0.04419417382415922f;  // (a-1)/sqrt(512)
    const float hispan = powf(1.0f / 512.0f, alpha - 1.0f);   // m - tau_hi

    {   // stage K, V (full token) — q is NOT staged (global, L2-resident)
        const float4* k4 = (const float4*)(kg + (size_t)t * 4096);
        const float4* v4 = (const float4*)(vg + (size_t)t * 4096);
#pragma unroll
        for (int u = 0; u < 4; ++u) {
            int idx = tid + 256 * u;
            ((float4*)ks)[idx] = k4[idx];
            ((float4*)vs)[idx] = v4[idx];
        }
    }
    __syncthreads();

    const int lane = tid & 63;
    const int w = tid >> 6;        // wave 0..3
    const int sub = lane >> 4;     // 16-lane group 0..3 (one row each)
    const int lx = lane & 15;

    const f32x2 zero2 = bc2(0.0f);
    const f32x2 one2  = bc2(1.0f);
    const f32x2 big2  = bc2(1e30f);

    const float* qt = qg + (size_t)t * 4096 + base;

    for (int it = 0; it < QROWS / 16; ++it) {
        const int il = it * 16 + w * 4 + sub;   // local row 0..127

        // q for this row, pre-scaled by (alpha-1)/sqrt(512); one address per
        // 16-lane group -> broadcast loads, values L2/L1-resident.
        float qv[8];
#pragma unroll
        for (int h = 0; h < 8; ++h) qv[h] = qt[h * 512 + il] * scl;

        // ---- scores (packed): lane cols j = lx*4 + 64*u + {0..3}
        f32x2 x2[16];
        f32x2 mv = bc2(-1e30f), sv = zero2;
#pragma unroll 2
        for (int u = 0; u < 8; ++u) {
            f32x2 A = zero2, B = zero2;
#pragma unroll
            for (int h = 0; h < 8; ++h) {
                float4 k4 = *(const float4*)&ks[h * 512 + lx * 4 + 64 * u];
                f32x2 qh2 = bc2(qv[h]);
                A = qh2 * mk2(k4.x, k4.y) + A;   // v_pk_fma_f32
                B = qh2 * mk2(k4.z, k4.w) + B;
            }
            x2[2 * u] = A;
            x2[2 * u + 1] = B;
            mv = max2(mv, max2(A, B));
            sv = sv + A + B;
        }
        float m = grp_max16(fmaxf(mv.x, mv.y));
        const float tlo = m - 1.0f;            // f(tlo) >= 1 always
        const float thi = m - hispan;          // f(thi) <= 1 always

        float tau;
        if (fast) {
            // seed: row mean, clamped into the bracket
            float s1a = grp_sum16(sv.x + sv.y);
            tau = fminf(fmaxf(s1a * (1.0f / 512.0f), tlo), thi);
            // exact active-set solves, packed sweeps
#pragma unroll
            for (int itr = 0; itr < NSOLVE; ++itr) {
                f32x2 tau2 = bc2(tau);
                f32x2 s1A = zero2, s1B = zero2;
                f32x2 s2A = zero2, s2B = zero2;
                f32x2 cA = zero2, cB = zero2;
#pragma unroll
                for (int j = 0; j < 16; j += 2) {
                    f32x2 rA = x2[j] - tau2;
                    f32x2 rB = x2[j + 1] - tau2;
                    f32x2 rpA = max2(rA, zero2);
                    f32x2 rpB = max2(rB, zero2);
                    s1A = s1A + rpA;
                    s1B = s1B + rpB;
                    s2A = rpA * rpA + s2A;
                    s2B = rpB * rpB + s2B;
                    cA = cA + min2(rpA * big2, one2);   // step(rp)
                    cB = cB + min2(rpB * big2, one2);
                }
                f32x2 s1v = s1A + s1B, s2v = s2A + s2B, cv = cA + cB;
                float s1 = grp_sum16(s1v.x + s1v.y);
                float s2 = grp_sum16(s2v.x + s2v.y);
                float nf = grp_sum16(cv.x + cv.y);
                float disc = fmaxf(fmaf(s1, s1, -nf * (s2 - 1.0f)), 0.0f);
                tau += (s1 - sqrtf(disc)) / fmaxf(nf, 1.0f);
                tau = fminf(fmaxf(tau, tlo), thi);
            }
        } else {
            // generic alpha: bisect + Newton (powf path, scalar components)
            tau = tlo;
            float dm = 1.0f - hispan;
#pragma unroll
            for (int bi = 0; bi < NBISECT; ++bi) {
                dm *= 0.5f;
                float tm = tau + dm;
                float f = 0.0f;
#pragma unroll
                for (int j = 0; j < 16; ++j) {
                    f += __powf(fmaxf(x2[j].x - tm, 0.0f), expo);
                    f += __powf(fmaxf(x2[j].y - tm, 0.0f), expo);
                }
                f = grp_sum16(f);
                if (f >= 1.0f) tau = tm;
            }
#pragma unroll
            for (int ni = 0; ni < NNEWTON; ++ni) {
                float f = 0.0f, g = 0.0f;
#pragma unroll
                for (int j = 0; j < 16; ++j) {
                    float r0 = fmaxf(x2[j].x - tau, 0.0f);
                    float rp0 = __powf(r0, expo - 1.0f);
                    g += rp0; f += rp0 * r0;
                    float r1 = fmaxf(x2[j].y - tau, 0.0f);
                    float rp1 = __powf(r1, expo - 1.0f);
                    g += rp1; f += rp1 * r1;
                }
                f = grp_sum16(f);
                g = grp_sum16(g);
                tau += (f - 1.0f) / fmaxf(expo * g, 1e-30f);
                tau = fminf(fmaxf(tau, tlo), thi);
            }
        }

        // ---- final (unnormalized) p into x2; S packed
        float S;
        if (fast) {
            f32x2 tau2 = bc2(tau);
            f32x2 SA = zero2, SB = zero2;
#pragma unroll
            for (int j = 0; j < 16; j += 2) {
                f32x2 rA = max2(x2[j] - tau2, zero2);
                f32x2 rB = max2(x2[j + 1] - tau2, zero2);
                f32x2 pA = rA * rA;
                f32x2 pB = rB * rB;
                x2[j] = pA;
                x2[j + 1] = pB;
                SA = SA + pA;
                SB = SB + pB;
            }
            f32x2 Sv = SA + SB;
            S = Sv.x + Sv.y;
        } else {
            float s0 = 0.0f;
#pragma unroll
            for (int j = 0; j < 16; ++j) {
                float p0 = __powf(fmaxf(x2[j].x - tau, 0.0f), expo);
                float p1 = __powf(fmaxf(x2[j].y - tau, 0.0f), expo);
                x2[j].x = p0; x2[j].y = p1;
                s0 += p0 + p1;
            }
            S = s0;
        }
        S = grp_sum16(S);
        const float invS = 1.0f / S;

        // ---- res[h,i] = invS * sum_j p[j] * v[h,j]  (packed fma, then hsum)
#pragma unroll
        for (int h = 0; h < 8; ++h) {
            f32x2 accA = zero2, accB = zero2;
#pragma unroll 2
            for (int u = 0; u < 8; ++u) {
                float4 v4 = *(const float4*)&vs[h * 512 + lx * 4 + 64 * u];
                accA = x2[2 * u] * mk2(v4.x, v4.y) + accA;
                accB = x2[2 * u + 1] * mk2(v4.z, v4.w) + accB;
            }
            float a = (accA.x + accA.y) + (accB.x + accB.y);
            a = grp_sum16(a) * invS;
            if (lx == h) resg[(size_t)t * 4096 + h * 512 + base + il] = a;
        }
    }
}

// ---------------------------------------------------------------------------
__global__ __launch_bounds__(256) void reduce_bias(
    const float* __restrict__ part, const float* __restrict__ bu,
    float* __restrict__ out, int MN, int S)
{
    int i = blockIdx.x * 256 + threadIdx.x;
    if (i >= MN) return;
    float a = bu[i & 511];
#pragma unroll
    for (int s = 0; s < 8; ++s) a += part[(size_t)s * MN + i];
    out[i] = a;
}

// ---------------------------------------------------------------------------
extern "C" void kernel_launch(void* const* d_in, const int* in_sizes, int n_in,
                              void* d_out, int out_size, void* d_ws, size_t ws_size,
                              hipStream_t stream)
{
    const float* x  = (const float*)d_in[0];
    const float* Wq = (const float*)d_in[1];
    const float* bq = (const float*)d_in[2];
    const float* Wk = (const float*)d_in[3];
    const float* bk = (const float*)d_in[4];
    const float* Wv = (const float*)d_in[5];
    const float* bv = (const float*)d_in[6];
    const float* Wu = (const float*)d_in[7];
    const float* bu = (const float*)d_in[8];
    const float* al = (const float*)d_in[9];
    float* out = (float*)d_out;
    float* ws = (float*)d_ws;

    // ws layout (floats): q[2M] | k[2M] | v[2M]
    // res aliases q: each attn block reads q rows only for its own disjoint
    // (t, base..base+127) slice and writes res to exactly that slice, with
    // each address read (same thread) before it is written. Split-K partials
    // alias k (dead after attn_entmax).
    float* q = ws;
    float* k = ws + 2097152;
    float* v = ws + 2 * 2097152;
    float* res = q;
    float* part = k;

    dim3 blk(256);

    dim3 g1(4096 / TN, 512 / TM, 1);
    gemm_tiled<<<g1, blk, 0, stream>>>(x, 512, Wq, 4096, q, 4096, 512, 4096, 512, bq);
    gemm_tiled<<<g1, blk, 0, stream>>>(x, 512, Wk, 4096, k, 4096, 512, 4096, 512, bk);
    gemm_tiled<<<g1, blk, 0, stream>>>(x, 512, Wv, 4096, v, 4096, 512, 4096, 512, bv);

    // fused scores + alpha-entmax + P*V^T, quarter token per block
    attn_entmax<<<dim3(2048), blk, 0, stream>>>(q, k, v, res, al);

    dim3 g3(512 / TN, 512 / TM, 8);
    gemm_tiled<<<g3, blk, 0, stream>>>(res, 4096, Wu, 512, part, 512, 512, 512, 512, nullptr);
    reduce_bias<<<dim3(262144 / 256), blk, 0, stream>>>(part, bu, out, 262144, 8);
}

// Round 16
// 320.967 us; speedup vs baseline: 3.2994x; 1.1250x over previous
//
#include <hip/hip_runtime.h>
#include <hip/hip_bf16.h>
#include <stdint.h>

// ---------------------------------------------------------------------------
// Packed 2xfp32 helpers — lower to v_pk_fma_f32 / v_pk_add_f32 / v_pk_max_f32
// ---------------------------------------------------------------------------
typedef float f32x2 __attribute__((ext_vector_type(2)));

__device__ __forceinline__ f32x2 mk2(float a, float b) { f32x2 r; r.x = a; r.y = b; return r; }
__device__ __forceinline__ f32x2 bc2(float a) { f32x2 r; r.x = a; r.y = a; return r; }
__device__ __forceinline__ f32x2 max2(f32x2 a, f32x2 b) {
#if __has_builtin(__builtin_elementwise_max)
    return __builtin_elementwise_max(a, b);
#else
    return mk2(fmaxf(a.x, b.x), fmaxf(a.y, b.y));
#endif
}
__device__ __forceinline__ f32x2 min2(f32x2 a, f32x2 b) {
#if __has_builtin(__builtin_elementwise_min)
    return __builtin_elementwise_min(a, b);
#else
    return mk2(fminf(a.x, b.x), fminf(a.y, b.y));
#endif
}

// ---------------------------------------------------------------------------
// f16 pair helpers (compile-proven in rounds 4/5) + v_dot2_f32_f16
// ---------------------------------------------------------------------------
typedef __fp16 half2v __attribute__((ext_vector_type(2)));

__device__ __forceinline__ half2v u2h(uint32_t u) {
    union { uint32_t u; half2v h; } c; c.u = u; return c.h;
}
__device__ __forceinline__ uint32_t pk(float lo, float hi) {
    union { uint32_t u; half2v h; } c;
    c.h = __builtin_amdgcn_cvt_pkrtz(lo, hi);
    return c.u;
}
#if __has_builtin(__builtin_amdgcn_fdot2)
__device__ __forceinline__ float dot2(uint32_t a, uint32_t b, float c) {
    return __builtin_amdgcn_fdot2(u2h(a), u2h(b), c, false);
}
#else
__device__ __forceinline__ float dot2(uint32_t a, uint32_t b, float c) {
    float d;
    asm("v_dot2_f32_f16 %0, %1, %2, %3" : "=v"(d) : "v"(a), "v"(b), "v"(c));
    return d;
}
#endif

// ---------------------------------------------------------------------------
// DPP helpers: reductions within each 16-lane row (VALU pipe, no LDS traffic)
// ---------------------------------------------------------------------------
template <int CTRL>
__device__ __forceinline__ float dppmov(float v) {
    return __int_as_float(__builtin_amdgcn_update_dpp(
        0, __float_as_int(v), CTRL, 0xF, 0xF, true));
}
__device__ __forceinline__ float grp_sum16(float v) {
    v += dppmov<0xB1>(v);   // quad_perm xor1
    v += dppmov<0x4E>(v);   // quad_perm xor2
    v += dppmov<0x124>(v);  // row_ror:4
    v += dppmov<0x128>(v);  // row_ror:8
    return v;
}
__device__ __forceinline__ float grp_max16(float v) {
    v = fmaxf(v, dppmov<0xB1>(v));
    v = fmaxf(v, dppmov<0x4E>(v));
    v = fmaxf(v, dppmov<0x124>(v));
    v = fmaxf(v, dppmov<0x128>(v));
    return v;
}

// ---------------------------------------------------------------------------
// fp32 tiled GEMM, inner loop packed (unchanged from round 12)
// ---------------------------------------------------------------------------
#define TM 64
#define TN 64
#define TK 16

__global__ __launch_bounds__(256) void gemm_tiled(
    const float* __restrict__ A, int lda,
    const float* __restrict__ B, int ldb,
    float* __restrict__ C, int ldc,
    int M, int N, int kc, const float* __restrict__ bias)
{
    __shared__ float As[TK][TM + 4];
    __shared__ float Bs[TK][TN + 4];
    const int tid = threadIdx.x;
    const int bm = blockIdx.y * TM;
    const int bn = blockIdx.x * TN;
    const int k0 = blockIdx.z * kc;
    C += (size_t)blockIdx.z * M * N;

    const int tx = tid & 15;
    const int ty = tid >> 4;

    f32x2 acc[4][2];
#pragma unroll
    for (int i = 0; i < 4; ++i) {
        if (bias) {
            acc[i][0] = mk2(bias[bn + tx * 4 + 0], bias[bn + tx * 4 + 1]);
            acc[i][1] = mk2(bias[bn + tx * 4 + 2], bias[bn + tx * 4 + 3]);
        } else {
            acc[i][0] = bc2(0.0f);
            acc[i][1] = bc2(0.0f);
        }
    }

    const int ar = tid >> 2;
    const int ac = (tid & 3) * 4;
    const int br = tid >> 4;
    const int bc = (tid & 15) * 4;

    for (int kt = k0; kt < k0 + kc; kt += TK) {
        float4 a = *(const float4*)&A[(size_t)(bm + ar) * lda + kt + ac];
        float4 b = *(const float4*)&B[(size_t)(kt + br) * ldb + bn + bc];
        As[ac + 0][ar] = a.x; As[ac + 1][ar] = a.y;
        As[ac + 2][ar] = a.z; As[ac + 3][ar] = a.w;
        *(float4*)&Bs[br][bc] = b;
        __syncthreads();
#pragma unroll
        for (int kk = 0; kk < TK; ++kk) {
            float4 a4 = *(const float4*)&As[kk][ty * 4];
            float4 b4 = *(const float4*)&Bs[kk][tx * 4];
            f32x2 b01 = mk2(b4.x, b4.y), b23 = mk2(b4.z, b4.w);
            float av[4] = {a4.x, a4.y, a4.z, a4.w};
#pragma unroll
            for (int i = 0; i < 4; ++i) {
                f32x2 ai = bc2(av[i]);
                acc[i][0] = ai * b01 + acc[i][0];   // v_pk_fma_f32
                acc[i][1] = ai * b23 + acc[i][1];
            }
        }
        __syncthreads();
    }
#pragma unroll
    for (int i = 0; i < 4; ++i) {
        float4 o = make_float4(acc[i][0].x, acc[i][0].y, acc[i][1].x, acc[i][1].y);
        *(float4*)&C[(size_t)(bm + ty * 4 + i) * ldc + bn + tx * 4] = o;
    }
}

// ---------------------------------------------------------------------------
// Fused quarter-token attn, round 15 = round-14 SKELETON VERBATIM (single
// x2[16] f32x2, one row per 16-lane group, #pragma unroll 2, (256,4)) with
// f16 dot2 data path:
//   K in LDS as f16 h-pairs [4][512]  -> scores dot2 sums 2 heads/instr,
//     32 conflict-free uint4 reads (vs 64 b128)
//   V in LDS as f16 j-pairs [8][256]  -> PV dot2 on col-pairs, p packed
//     IN PLACE into x2[j].x (array count stays 1 -> SROA-safe)
//   q from global, scaled by 4*(a-1)/sqrt(512): p in [0,24] avoids f16
//     denormals; TGT=16 / bracket x4 (affine rescale, identical trajectory)
// LDS 16 KB. WRITE_SIZE == 8192 is the no-scratch tripwire.
// ---------------------------------------------------------------------------
#define QROWS 128
#define NSOLVE 3
#define NBISECT 3
#define NNEWTON 6

__global__ __launch_bounds__(256, 4) void attn_entmax(
    const float* __restrict__ qg, const float* __restrict__ kg,
    const float* __restrict__ vg, float* resg,
    const float* __restrict__ alpha_p)
{
    __shared__ uint32_t ks16[4 * 512];   // [h2][j]  = (k[2h2][j], k[2h2+1][j])
    __shared__ uint32_t vs16[8 * 256];   // [h][j2]  = (v[h][2j2], v[h][2j2+1])
    const int t = blockIdx.x >> 2;
    const int base = (blockIdx.x & 3) * QROWS;
    const int tid = threadIdx.x;

    const float alpha = alpha_p[0];
    const float expo = 1.0f / (alpha - 1.0f);      // = 2 for alpha=1.5 (exact)
    const bool fast = (expo == 2.0f);
    const float scl = (alpha - 1.0f) * 0.04419417382415922f;  // (a-1)/sqrt(512)
    const float hispan = powf(1.0f / 512.0f, alpha - 1.0f);

    const float qmul = fast ? 4.0f * scl : scl;    // fast path: x' = 4x
    const float TGT  = fast ? 16.0f : 1.0f;
    const float loO  = fast ? 4.0f : 1.0f;         // tau >= m - loO
    const float hiO  = (fast ? 4.0f : 1.0f) * hispan;

    {   // ---- stage K (h-pair packed) and V (j-pair packed); q not staged
        const float4* k4g = (const float4*)(kg + (size_t)t * 4096);
        const float4* v4g = (const float4*)(vg + (size_t)t * 4096);
#pragma unroll
        for (int a0 = 0; a0 < 2; ++a0) {
            int idx = tid + 256 * a0;          // 0..511: h2 = idx>>7, j4 = idx&127
            int h2 = idx >> 7, j4 = idx & 127;
            float4 g0 = k4g[(2 * h2) * 128 + j4];
            float4 g1 = k4g[(2 * h2 + 1) * 128 + j4];
            uint4 p4 = make_uint4(pk(g0.x, g1.x), pk(g0.y, g1.y),
                                  pk(g0.z, g1.z), pk(g0.w, g1.w));
            *(uint4*)&ks16[h2 * 512 + j4 * 4] = p4;
        }
#pragma unroll
        for (int a0 = 0; a0 < 4; ++a0) {
            int f = tid + 256 * a0;            // 0..1023: h = f>>7, j4 = f&127
            int h = f >> 7, j4 = f & 127;
            float4 g = v4g[h * 128 + j4];
            uint2 p2 = make_uint2(pk(g.x, g.y), pk(g.z, g.w));
            *(uint2*)&vs16[h * 256 + j4 * 2] = p2;
        }
    }
    __syncthreads();

    const int lane = tid & 63;
    const int w = tid >> 6;        // wave 0..3
    const int sub = lane >> 4;     // 16-lane group 0..3 (one row each)
    const int lx = lane & 15;

    const f32x2 zero2 = bc2(0.0f);
    const f32x2 one2  = bc2(1.0f);
    const f32x2 big2  = bc2(1e30f);

    const float* qt = qg + (size_t)t * 4096 + base;

    for (int it = 0; it < QROWS / 16; ++it) {
        const int il = it * 16 + w * 4 + sub;   // local row 0..127

        // q for this row, scaled, packed to f16 h-pairs (broadcast loads)
        uint32_t qp[4];
#pragma unroll
        for (int h2 = 0; h2 < 4; ++h2)
            qp[h2] = pk(qt[(2 * h2) * 512 + il] * qmul,
                        qt[(2 * h2 + 1) * 512 + il] * qmul);

        // ---- scores via dot2: lane cols j = lx*4 + 64*u + {0..3}
        f32x2 x2[16];
        f32x2 mv = bc2(-1e30f), sv = zero2;
#pragma unroll 2
        for (int u = 0; u < 8; ++u) {
            float a0 = 0, a1 = 0, a2 = 0, a3 = 0;
#pragma unroll
            for (int h2 = 0; h2 < 4; ++h2) {
                uint4 kk = *(const uint4*)&ks16[h2 * 512 + lx * 4 + 64 * u];
                uint32_t qh = qp[h2];
                a0 = dot2(kk.x, qh, a0);
                a1 = dot2(kk.y, qh, a1);
                a2 = dot2(kk.z, qh, a2);
                a3 = dot2(kk.w, qh, a3);
            }
            f32x2 A = mk2(a0, a1), B = mk2(a2, a3);
            x2[2 * u] = A;
            x2[2 * u + 1] = B;
            mv = max2(mv, max2(A, B));
            sv = sv + A + B;
        }
        float m = grp_max16(fmaxf(mv.x, mv.y));
        const float tlo = m - loO;             // f(tlo) >= TGT always
        const float thi = m - hiO;             // f(thi) <= TGT always

        float tau;
        if (fast) {
            // seed: row mean, clamped into the bracket
            float s1a = grp_sum16(sv.x + sv.y);
            tau = fminf(fmaxf(s1a * (1.0f / 512.0f), tlo), thi);
            // exact active-set solves, packed sweeps
#pragma unroll
            for (int itr = 0; itr < NSOLVE; ++itr) {
                f32x2 tau2 = bc2(tau);
                f32x2 s1A = zero2, s1B = zero2;
                f32x2 s2A = zero2, s2B = zero2;
                f32x2 cA = zero2, cB = zero2;
#pragma unroll
                for (int j = 0; j < 16; j += 2) {
                    f32x2 rA = x2[j] - tau2;
                    f32x2 rB = x2[j + 1] - tau2;
                    f32x2 rpA = max2(rA, zero2);
                    f32x2 rpB = max2(rB, zero2);
                    s1A = s1A + rpA;
                    s1B = s1B + rpB;
                    s2A = rpA * rpA + s2A;
                    s2B = rpB * rpB + s2B;
                    cA = cA + min2(rpA * big2, one2);   // step(rp)
                    cB = cB + min2(rpB * big2, one2);
                }
                f32x2 s1v = s1A + s1B, s2v = s2A + s2B, cv = cA + cB;
                float s1 = grp_sum16(s1v.x + s1v.y);
                float s2 = grp_sum16(s2v.x + s2v.y);
                float nf = grp_sum16(cv.x + cv.y);
                float disc = fmaxf(fmaf(s1, s1, -nf * (s2 - TGT)), 0.0f);
                tau += (s1 - sqrtf(disc)) / fmaxf(nf, 1.0f);
                tau = fminf(fmaxf(tau, tlo), thi);
            }
        } else {
            // generic alpha: bisect + Newton (powf path, scalar components)
            tau = tlo;
            float dm = loO - hiO;
#pragma unroll
            for (int bi = 0; bi < NBISECT; ++bi) {
                dm *= 0.5f;
                float tm = tau + dm;
                float f = 0.0f;
#pragma unroll
                for (int j = 0; j < 16; ++j) {
                    f += __powf(fmaxf(x2[j].x - tm, 0.0f), expo);
                    f += __powf(fmaxf(x2[j].y - tm, 0.0f), expo);
                }
                f = grp_sum16(f);
                if (f >= TGT) tau = tm;
            }
#pragma unroll
            for (int ni = 0; ni < NNEWTON; ++ni) {
                float f = 0.0f, g = 0.0f;
#pragma unroll
                for (int j = 0; j < 16; ++j) {
                    float r0 = fmaxf(x2[j].x - tau, 0.0f);
                    float rp0 = __powf(r0, expo - 1.0f);
                    g += rp0; f += rp0 * r0;
                    float r1 = fmaxf(x2[j].y - tau, 0.0f);
                    float rp1 = __powf(r1, expo - 1.0f);
                    g += rp1; f += rp1 * r1;
                }
                f = grp_sum16(f);
                g = grp_sum16(g);
                tau += (f - TGT) / fmaxf(expo * g, 1e-30f);
                tau = fminf(fmaxf(tau, tlo), thi);
            }
        }

        // ---- final p; S; pack p to f16 pairs IN PLACE (x2[j].x = pair bits)
        float S;
        if (fast) {
            f32x2 tau2 = bc2(tau);
            f32x2 SA = zero2, SB = zero2;
#pragma unroll
            for (int j = 0; j < 16; j += 2) {
                f32x2 rA = max2(x2[j] - tau2, zero2);
                f32x2 rB = max2(x2[j + 1] - tau2, zero2);
                f32x2 pA = rA * rA;
                f32x2 pB = rB * rB;
                SA = SA + pA;
                SB = SB + pB;
                x2[j].x = __uint_as_float(pk(pA.x, pA.y));
                x2[j + 1].x = __uint_as_float(pk(pB.x, pB.y));
            }
            f32x2 Sv = SA + SB;
            S = Sv.x + Sv.y;
        } else {
            float s0 = 0.0f;
#pragma unroll
            for (int j = 0; j < 16; ++j) {
                float p0 = __powf(fmaxf(x2[j].x - tau, 0.0f), expo);
                float p1 = __powf(fmaxf(x2[j].y - tau, 0.0f), expo);
                s0 += p0 + p1;
                x2[j].x = __uint_as_float(pk(p0, p1));
            }
            S = s0;
        }
        S = grp_sum16(S);
        const float invS = 1.0f / S;

        // ---- res[h,i] = invS * sum_j p[j] v[h,j] via dot2 on j-pairs
#pragma unroll
        for (int h = 0; h < 8; ++h) {
            float aA = 0.0f, aB = 0.0f;
#pragma unroll 2
            for (int u = 0; u < 8; ++u) {
                uint2 vv = *(const uint2*)&vs16[h * 256 + lx * 2 + 32 * u];
                aA = dot2(__float_as_uint(x2[2 * u].x), vv.x, aA);
                aB = dot2(__float_as_uint(x2[2 * u + 1].x), vv.y, aB);
            }
            float a = grp_sum16(aA + aB) * invS;
            if (lx == h) resg[(size_t)t * 4096 + h * 512 + base + il] = a;
        }
    }
}

// ---------------------------------------------------------------------------
__global__ __launch_bounds__(256) void reduce_bias(
    const float* __restrict__ part, const float* __restrict__ bu,
    float* __restrict__ out, int MN, int S)
{
    int i = blockIdx.x * 256 + threadIdx.x;
    if (i >= MN) return;
    float a = bu[i & 511];
#pragma unroll
    for (int s = 0; s < 8; ++s) a += part[(size_t)s * MN + i];
    out[i] = a;
}

// ---------------------------------------------------------------------------
extern "C" void kernel_launch(void* const* d_in, const int* in_sizes, int n_in,
                              void* d_out, int out_size, void* d_ws, size_t ws_size,
                              hipStream_t stream)
{
    const float* x  = (const float*)d_in[0];
    const float* Wq = (const float*)d_in[1];
    const float* bq = (const float*)d_in[2];
    const float* Wk = (const float*)d_in[3];
    const float* bk = (const float*)d_in[4];
    const float* Wv = (const float*)d_in[5];
    const float* bv = (const float*)d_in[6];
    const float* Wu = (const float*)d_in[7];
    const float* bu = (const float*)d_in[8];
    const float* al = (const float*)d_in[9];
    float* out = (float*)d_out;
    float* ws = (float*)d_ws;

    // ws layout (floats): q[2M] | k[2M] | v[2M]
    // res aliases q: each attn block reads q rows only for its own disjoint
    // (t, base..+127) slice, each address read (same wave) before written.
    // Split-K partials alias k (dead after attn_entmax).
    float* q = ws;
    float* k = ws + 2097152;
    float* v = ws + 2 * 2097152;
    float* res = q;
    float* part = k;

    dim3 blk(256);

    dim3 g1(4096 / TN, 512 / TM, 1);
    gemm_tiled<<<g1, blk, 0, stream>>>(x, 512, Wq, 4096, q, 4096, 512, 4096, 512, bq);
    gemm_tiled<<<g1, blk, 0, stream>>>(x, 512, Wk, 4096, k, 4096, 512, 4096, 512, bk);
    gemm_tiled<<<g1, blk, 0, stream>>>(x, 512, Wv, 4096, v, 4096, 512, 4096, 512, bv);

    // fused scores + alpha-entmax + P*V^T, quarter token per block
    attn_entmax<<<dim3(2048), blk, 0, stream>>>(q, k, v, res, al);

    dim3 g3(512 / TN, 512 / TM, 8);
    gemm_tiled<<<g3, blk, 0, stream>>>(res, 4096, Wu, 512, part, 512, 512, 512, 512, nullptr);
    reduce_bias<<<dim3(262144 / 256), blk, 0, stream>>>(part, bu, out, 262144, 8);
}

// Round 17
// 250.578 us; speedup vs baseline: 4.2263x; 1.2809x over previous
//
#include <hip/hip_runtime.h>
#include <hip/hip_bf16.h>
#include <stdint.h>

// ---------------------------------------------------------------------------
// Packed 2xfp32 helpers — lower to v_pk_fma_f32 / v_pk_add_f32 / v_pk_max_f32
// ---------------------------------------------------------------------------
typedef float f32x2 __attribute__((ext_vector_type(2)));

__device__ __forceinline__ f32x2 mk2(float a, float b) { f32x2 r; r.x = a; r.y = b; return r; }
__device__ __forceinline__ f32x2 bc2(float a) { f32x2 r; r.x = a; r.y = a; return r; }
__device__ __forceinline__ f32x2 max2(f32x2 a, f32x2 b) {
#if __has_builtin(__builtin_elementwise_max)
    return __builtin_elementwise_max(a, b);
#else
    return mk2(fmaxf(a.x, b.x), fmaxf(a.y, b.y));
#endif
}
__device__ __forceinline__ f32x2 min2(f32x2 a, f32x2 b) {
#if __has_builtin(__builtin_elementwise_min)
    return __builtin_elementwise_min(a, b);
#else
    return mk2(fminf(a.x, b.x), fminf(a.y, b.y));
#endif
}

// ---------------------------------------------------------------------------
// f16 helpers + v_dot2_f32_f16 (attn) and MFMA fragment types (GEMM)
// ---------------------------------------------------------------------------
typedef __fp16 half2v __attribute__((ext_vector_type(2)));
typedef __fp16 f16x8v __attribute__((ext_vector_type(8)));
typedef float f32x4v __attribute__((ext_vector_type(4)));

__device__ __forceinline__ half2v u2h(uint32_t u) {
    union { uint32_t u; half2v h; } c; c.u = u; return c.h;
}
__device__ __forceinline__ uint32_t pk(float lo, float hi) {
    union { uint32_t u; half2v h; } c;
    c.h = __builtin_amdgcn_cvt_pkrtz(lo, hi);
    return c.u;
}
__device__ __forceinline__ f16x8v u4h8(uint4 u) {
    union { uint4 u; f16x8v h; } c; c.u = u; return c.h;
}
#if __has_builtin(__builtin_amdgcn_fdot2)
__device__ __forceinline__ float dot2(uint32_t a, uint32_t b, float c) {
    return __builtin_amdgcn_fdot2(u2h(a), u2h(b), c, false);
}
#else
__device__ __forceinline__ float dot2(uint32_t a, uint32_t b, float c) {
    float d;
    asm("v_dot2_f32_f16 %0, %1, %2, %3" : "=v"(d) : "v"(a), "v"(b), "v"(c));
    return d;
}
#endif

// ---------------------------------------------------------------------------
// DPP helpers: reductions within each 16-lane row (VALU pipe, no LDS traffic)
// ---------------------------------------------------------------------------
template <int CTRL>
__device__ __forceinline__ float dppmov(float v) {
    return __int_as_float(__builtin_amdgcn_update_dpp(
        0, __float_as_int(v), CTRL, 0xF, 0xF, true));
}
__device__ __forceinline__ float grp_sum16(float v) {
    v += dppmov<0xB1>(v);   // quad_perm xor1
    v += dppmov<0x4E>(v);   // quad_perm xor2
    v += dppmov<0x124>(v);  // row_ror:4
    v += dppmov<0x128>(v);  // row_ror:8
    return v;
}
__device__ __forceinline__ float grp_max16(float v) {
    v = fmaxf(v, dppmov<0xB1>(v));
    v = fmaxf(v, dppmov<0x4E>(v));
    v = fmaxf(v, dppmov<0x124>(v));
    v = fmaxf(v, dppmov<0x128>(v));
    return v;
}

// ---------------------------------------------------------------------------
// MFMA f16 tiled GEMM: C = A(MxK) * B(KxN) (+bias), fp32 I/O, f16 compute,
// fp32 accumulate. 64x64 tile, 4 waves (wave w owns rows 16w..16w+15),
// K-step 32 via v_mfma_f32_16x16x32_f16.
// Fragment layouts (gfx94x/95x 16x16x32 family):
//   A: lane l holds A[row = l&15][k = (l>>4)*8 + 0..7]   (b128 from LDS)
//   B: lane l holds B[k = (l>>4)*8 + 0..7][col = l&15]   (B stored transposed)
//   D: lane l holds D[row = (l>>4)*4 + reg][col = l&15]  (guide-verified m89)
// LDS tiles f16, row stride 56 f16 = 112 B (16B-aligned, low-conflict).
// ---------------------------------------------------------------------------
__global__ __launch_bounds__(256) void gemm_mfma(
    const float* __restrict__ A, int lda,
    const float* __restrict__ B, int ldb,
    float* __restrict__ C, int ldc,
    int M, int N, int kc, const float* __restrict__ bias)
{
    __shared__ uint32_t AhU[64 * 28];   // [row][k-pair], stride 28 uints
    __shared__ uint32_t BhU[64 * 28];   // [col][k-pair] (transposed)
    const int tid = threadIdx.x;
    const int bm = blockIdx.y * 64;
    const int bn = blockIdx.x * 64;
    const int k0 = blockIdx.z * kc;
    C += (size_t)blockIdx.z * M * N;

    const int lane = tid & 63;
    const int w = tid >> 6;
    const int lr = lane & 15;       // A-row / B-col / D-col within tile
    const int lg = lane >> 4;       // k-group 0..3

    f32x4v acc[4];
#pragma unroll
    for (int nt = 0; nt < 4; ++nt) acc[nt] = (f32x4v)(0.0f);

    const int sar = tid >> 2;              // A stage: row 0..63
    const int sak = (tid & 3) * 8;         // A stage: k offset 0,8,16,24
    const int sbn = (tid & 15) * 4;        // B stage: col 0..60
    const int sbk = (tid >> 4) * 2;        // B stage: k 0..30 (even)

    for (int kt = k0; kt < k0 + kc; kt += 32) {
        float4 a0 = *(const float4*)&A[(size_t)(bm + sar) * lda + kt + sak];
        float4 a1 = *(const float4*)&A[(size_t)(bm + sar) * lda + kt + sak + 4];
        float4 b0 = *(const float4*)&B[(size_t)(kt + sbk) * ldb + bn + sbn];
        float4 b1 = *(const float4*)&B[(size_t)(kt + sbk + 1) * ldb + bn + sbn];
        __syncthreads();   // previous iter's fragment reads complete
        *(uint4*)&AhU[sar * 28 + (tid & 3) * 4] =
            make_uint4(pk(a0.x, a0.y), pk(a0.z, a0.w),
                       pk(a1.x, a1.y), pk(a1.z, a1.w));
        BhU[(sbn + 0) * 28 + (tid >> 4)] = pk(b0.x, b1.x);
        BhU[(sbn + 1) * 28 + (tid >> 4)] = pk(b0.y, b1.y);
        BhU[(sbn + 2) * 28 + (tid >> 4)] = pk(b0.z, b1.z);
        BhU[(sbn + 3) * 28 + (tid >> 4)] = pk(b0.w, b1.w);
        __syncthreads();

        f16x8v af = u4h8(*(const uint4*)&AhU[(16 * w + lr) * 28 + lg * 4]);
#pragma unroll
        for (int nt = 0; nt < 4; ++nt) {
            f16x8v bf = u4h8(*(const uint4*)&BhU[(nt * 16 + lr) * 28 + lg * 4]);
            acc[nt] = __builtin_amdgcn_mfma_f32_16x16x32_f16(af, bf, acc[nt], 0, 0, 0);
        }
    }

#pragma unroll
    for (int nt = 0; nt < 4; ++nt) {
        const int col = bn + nt * 16 + lr;
        const float badd = bias ? bias[col] : 0.0f;
#pragma unroll
        for (int reg = 0; reg < 4; ++reg) {
            const int row = bm + 16 * w + 4 * lg + reg;
            C[(size_t)row * ldc + col] = acc[nt][reg] + badd;
        }
    }
}

// ---------------------------------------------------------------------------
// Fused quarter-token attn — round-15 kernel VERBATIM (204 us, VGPR 60,
// zero scratch): f16 dot2 scores/PV, single x2[16], one row per 16-lane
// group, #pragma unroll 2, mean-seeded exact active-set solver.
// ---------------------------------------------------------------------------
#define QROWS 128
#define NSOLVE 3
#define NBISECT 3
#define NNEWTON 6

__global__ __launch_bounds__(256, 4) void attn_entmax(
    const float* __restrict__ qg, const float* __restrict__ kg,
    const float* __restrict__ vg, float* resg,
    const float* __restrict__ alpha_p)
{
    __shared__ uint32_t ks16[4 * 512];   // [h2][j]  = (k[2h2][j], k[2h2+1][j])
    __shared__ uint32_t vs16[8 * 256];   // [h][j2]  = (v[h][2j2], v[h][2j2+1])
    const int t = blockIdx.x >> 2;
    const int base = (blockIdx.x & 3) * QROWS;
    const int tid = threadIdx.x;

    const float alpha = alpha_p[0];
    const float expo = 1.0f / (alpha - 1.0f);      // = 2 for alpha=1.5 (exact)
    const bool fast = (expo == 2.0f);
    const float scl = (alpha - 1.0f) * 0.04419417382415922f;  // (a-1)/sqrt(512)
    const float hispan = powf(1.0f / 512.0f, alpha - 1.0f);

    const float qmul = fast ? 4.0f * scl : scl;    // fast path: x' = 4x
    const float TGT  = fast ? 16.0f : 1.0f;
    const float loO  = fast ? 4.0f : 1.0f;         // tau >= m - loO
    const float hiO  = (fast ? 4.0f : 1.0f) * hispan;

    {   // ---- stage K (h-pair packed) and V (j-pair packed); q not staged
        const float4* k4g = (const float4*)(kg + (size_t)t * 4096);
        const float4* v4g = (const float4*)(vg + (size_t)t * 4096);
#pragma unroll
        for (int a0 = 0; a0 < 2; ++a0) {
            int idx = tid + 256 * a0;          // 0..511: h2 = idx>>7, j4 = idx&127
            int h2 = idx >> 7, j4 = idx & 127;
            float4 g0 = k4g[(2 * h2) * 128 + j4];
            float4 g1 = k4g[(2 * h2 + 1) * 128 + j4];
            uint4 p4 = make_uint4(pk(g0.x, g1.x), pk(g0.y, g1.y),
                                  pk(g0.z, g1.z), pk(g0.w, g1.w));
            *(uint4*)&ks16[h2 * 512 + j4 * 4] = p4;
        }
#pragma unroll
        for (int a0 = 0; a0 < 4; ++a0) {
            int f = tid + 256 * a0;            // 0..1023: h = f>>7, j4 = f&127
            int h = f >> 7, j4 = f & 127;
            float4 g = v4g[h * 128 + j4];
            uint2 p2 = make_uint2(pk(g.x, g.y), pk(g.z, g.w));
            *(uint2*)&vs16[h * 256 + j4 * 2] = p2;
        }
    }
    __syncthreads();

    const int lane = tid & 63;
    const int w = tid >> 6;        // wave 0..3
    const int sub = lane >> 4;     // 16-lane group 0..3 (one row each)
    const int lx = lane & 15;

    const f32x2 zero2 = bc2(0.0f);
    const f32x2 one2  = bc2(1.0f);
    const f32x2 big2  = bc2(1e30f);

    const float* qt = qg + (size_t)t * 4096 + base;

    for (int it = 0; it < QROWS / 16; ++it) {
        const int il = it * 16 + w * 4 + sub;   // local row 0..127

        // q for this row, scaled, packed to f16 h-pairs (broadcast loads)
        uint32_t qp[4];
#pragma unroll
        for (int h2 = 0; h2 < 4; ++h2)
            qp[h2] = pk(qt[(2 * h2) * 512 + il] * qmul,
                        qt[(2 * h2 + 1) * 512 + il] * qmul);

        // ---- scores via dot2: lane cols j = lx*4 + 64*u + {0..3}
        f32x2 x2[16];
        f32x2 mv = bc2(-1e30f), sv = zero2;
#pragma unroll 2
        for (int u = 0; u < 8; ++u) {
            float a0 = 0, a1 = 0, a2 = 0, a3 = 0;
#pragma unroll
            for (int h2 = 0; h2 < 4; ++h2) {
                uint4 kk = *(const uint4*)&ks16[h2 * 512 + lx * 4 + 64 * u];
                uint32_t qh = qp[h2];
                a0 = dot2(kk.x, qh, a0);
                a1 = dot2(kk.y, qh, a1);
                a2 = dot2(kk.z, qh, a2);
                a3 = dot2(kk.w, qh, a3);
            }
            f32x2 A = mk2(a0, a1), B = mk2(a2, a3);
            x2[2 * u] = A;
            x2[2 * u + 1] = B;
            mv = max2(mv, max2(A, B));
            sv = sv + A + B;
        }
        float m = grp_max16(fmaxf(mv.x, mv.y));
        const float tlo = m - loO;             // f(tlo) >= TGT always
        const float thi = m - hiO;             // f(thi) <= TGT always

        float tau;
        if (fast) {
            // seed: row mean, clamped into the bracket
            float s1a = grp_sum16(sv.x + sv.y);
            tau = fminf(fmaxf(s1a * (1.0f / 512.0f), tlo), thi);
            // exact active-set solves, packed sweeps
#pragma unroll
            for (int itr = 0; itr < NSOLVE; ++itr) {
                f32x2 tau2 = bc2(tau);
                f32x2 s1A = zero2, s1B = zero2;
                f32x2 s2A = zero2, s2B = zero2;
                f32x2 cA = zero2, cB = zero2;
#pragma unroll
                for (int j = 0; j < 16; j += 2) {
                    f32x2 rA = x2[j] - tau2;
                    f32x2 rB = x2[j + 1] - tau2;
                    f32x2 rpA = max2(rA, zero2);
                    f32x2 rpB = max2(rB, zero2);
                    s1A = s1A + rpA;
                    s1B = s1B + rpB;
                    s2A = rpA * rpA + s2A;
                    s2B = rpB * rpB + s2B;
                    cA = cA + min2(rpA * big2, one2);   // step(rp)
                    cB = cB + min2(rpB * big2, one2);
                }
                f32x2 s1v = s1A + s1B, s2v = s2A + s2B, cv = cA + cB;
                float s1 = grp_sum16(s1v.x + s1v.y);
                float s2 = grp_sum16(s2v.x + s2v.y);
                float nf = grp_sum16(cv.x + cv.y);
                float disc = fmaxf(fmaf(s1, s1, -nf * (s2 - TGT)), 0.0f);
                tau += (s1 - sqrtf(disc)) / fmaxf(nf, 1.0f);
                tau = fminf(fmaxf(tau, tlo), thi);
            }
        } else {
            // generic alpha: bisect + Newton (powf path, scalar components)
            tau = tlo;
            float dm = loO - hiO;
#pragma unroll
            for (int bi = 0; bi < NBISECT; ++bi) {
                dm *= 0.5f;
                float tm = tau + dm;
                float f = 0.0f;
#pragma unroll
                for (int j = 0; j < 16; ++j) {
                    f += __powf(fmaxf(x2[j].x - tm, 0.0f), expo);
                    f += __powf(fmaxf(x2[j].y - tm, 0.0f), expo);
                }
                f = grp_sum16(f);
                if (f >= TGT) tau = tm;
            }
#pragma unroll
            for (int ni = 0; ni < NNEWTON; ++ni) {
                float f = 0.0f, g = 0.0f;
#pragma unroll
                for (int j = 0; j < 16; ++j) {
                    float r0 = fmaxf(x2[j].x - tau, 0.0f);
                    float rp0 = __powf(r0, expo - 1.0f);
                    g += rp0; f += rp0 * r0;
                    float r1 = fmaxf(x2[j].y - tau, 0.0f);
                    float rp1 = __powf(r1, expo - 1.0f);
                    g += rp1; f += rp1 * r1;
                }
                f = grp_sum16(f);
                g = grp_sum16(g);
                tau += (f - TGT) / fmaxf(expo * g, 1e-30f);
                tau = fminf(fmaxf(tau, tlo), thi);
            }
        }

        // ---- final p; S; pack p to f16 pairs IN PLACE (x2[j].x = pair bits)
        float S;
        if (fast) {
            f32x2 tau2 = bc2(tau);
            f32x2 SA = zero2, SB = zero2;
#pragma unroll
            for (int j = 0; j < 16; j += 2) {
                f32x2 rA = max2(x2[j] - tau2, zero2);
                f32x2 rB = max2(x2[j + 1] - tau2, zero2);
                f32x2 pA = rA * rA;
                f32x2 pB = rB * rB;
                SA = SA + pA;
                SB = SB + pB;
                x2[j].x = __uint_as_float(pk(pA.x, pA.y));
                x2[j + 1].x = __uint_as_float(pk(pB.x, pB.y));
            }
            f32x2 Sv = SA + SB;
            S = Sv.x + Sv.y;
        } else {
            float s0 = 0.0f;
#pragma unroll
            for (int j = 0; j < 16; ++j) {
                float p0 = __powf(fmaxf(x2[j].x - tau, 0.0f), expo);
                float p1 = __powf(fmaxf(x2[j].y - tau, 0.0f), expo);
                s0 += p0 + p1;
                x2[j].x = __uint_as_float(pk(p0, p1));
            }
            S = s0;
        }
        S = grp_sum16(S);
        const float invS = 1.0f / S;

        // ---- res[h,i] = invS * sum_j p[j] v[h,j] via dot2 on j-pairs
#pragma unroll
        for (int h = 0; h < 8; ++h) {
            float aA = 0.0f, aB = 0.0f;
#pragma unroll 2
            for (int u = 0; u < 8; ++u) {
                uint2 vv = *(const uint2*)&vs16[h * 256 + lx * 2 + 32 * u];
                aA = dot2(__float_as_uint(x2[2 * u].x), vv.x, aA);
                aB = dot2(__float_as_uint(x2[2 * u + 1].x), vv.y, aB);
            }
            float a = grp_sum16(aA + aB) * invS;
            if (lx == h) resg[(size_t)t * 4096 + h * 512 + base + il] = a;
        }
    }
}

// ---------------------------------------------------------------------------
__global__ __launch_bounds__(256) void reduce_bias(
    const float* __restrict__ part, const float* __restrict__ bu,
    float* __restrict__ out, int MN, int S)
{
    int i = blockIdx.x * 256 + threadIdx.x;
    if (i >= MN) return;
    float a = bu[i & 511];
#pragma unroll
    for (int s = 0; s < 8; ++s) a += part[(size_t)s * MN + i];
    out[i] = a;
}

// ---------------------------------------------------------------------------
extern "C" void kernel_launch(void* const* d_in, const int* in_sizes, int n_in,
                              void* d_out, int out_size, void* d_ws, size_t ws_size,
                              hipStream_t stream)
{
    const float* x  = (const float*)d_in[0];
    const float* Wq = (const float*)d_in[1];
    const float* bq = (const float*)d_in[2];
    const float* Wk = (const float*)d_in[3];
    const float* bk = (const float*)d_in[4];
    const float* Wv = (const float*)d_in[5];
    const float* bv = (const float*)d_in[6];
    const float* Wu = (const float*)d_in[7];
    const float* bu = (const float*)d_in[8];
    const float* al = (const float*)d_in[9];
    float* out = (float*)d_out;
    float* ws = (float*)d_ws;

    // ws layout (floats): q[2M] | k[2M] | v[2M]
    // res aliases q: each attn block reads q rows only for its own disjoint
    // (t, base..+127) slice, each address read (same wave) before written.
    // Split-K partials alias k (dead after attn_entmax).
    float* q = ws;
    float* k = ws + 2097152;
    float* v = ws + 2 * 2097152;
    float* res = q;
    float* part = k;

    dim3 blk(256);

    // QKV projections via MFMA f16 (fp32 accumulate)
    dim3 g1(4096 / 64, 512 / 64, 1);
    gemm_mfma<<<g1, blk, 0, stream>>>(x, 512, Wq, 4096, q, 4096, 512, 4096, 512, bq);
    gemm_mfma<<<g1, blk, 0, stream>>>(x, 512, Wk, 4096, k, 4096, 512, 4096, 512, bk);
    gemm_mfma<<<g1, blk, 0, stream>>>(x, 512, Wv, 4096, v, 4096, 512, 4096, 512, bv);

    // fused scores + alpha-entmax + P*V^T, quarter token per block
    attn_entmax<<<dim3(2048), blk, 0, stream>>>(q, k, v, res, al);

    // out = res @ Wu + bu, split-K=8 via MFMA, then reduce
    dim3 g3(512 / 64, 512 / 64, 8);
    gemm_mfma<<<g3, blk, 0, stream>>>(res, 4096, Wu, 512, part, 512, 512, 512, 512, nullptr);
    reduce_bias<<<dim3(262144 / 256), blk, 0, stream>>>(part, bu, out, 262144, 8);
}

// Round 18
// 232.171 us; speedup vs baseline: 4.5613x; 1.0793x over previous
//
#include <hip/hip_runtime.h>
#include <hip/hip_bf16.h>
#include <stdint.h>

// ---------------------------------------------------------------------------
// Packed 2xfp32 helpers — lower to v_pk_fma_f32 / v_pk_add_f32 / v_pk_max_f32
// ---------------------------------------------------------------------------
typedef float f32x2 __attribute__((ext_vector_type(2)));

__device__ __forceinline__ f32x2 mk2(float a, float b) { f32x2 r; r.x = a; r.y = b; return r; }
__device__ __forceinline__ f32x2 bc2(float a) { f32x2 r; r.x = a; r.y = a; return r; }
__device__ __forceinline__ f32x2 max2(f32x2 a, f32x2 b) {
#if __has_builtin(__builtin_elementwise_max)
    return __builtin_elementwise_max(a, b);
#else
    return mk2(fmaxf(a.x, b.x), fmaxf(a.y, b.y));
#endif
}
__device__ __forceinline__ f32x2 min2(f32x2 a, f32x2 b) {
#if __has_builtin(__builtin_elementwise_min)
    return __builtin_elementwise_min(a, b);
#else
    return mk2(fminf(a.x, b.x), fminf(a.y, b.y));
#endif
}

// ---------------------------------------------------------------------------
// f16 helpers + v_dot2_f32_f16 (attn) and MFMA fragment types (GEMM)
// ---------------------------------------------------------------------------
typedef __fp16 half2v __attribute__((ext_vector_type(2)));
typedef __fp16 f16x8v __attribute__((ext_vector_type(8)));
typedef float f32x4v __attribute__((ext_vector_type(4)));

__device__ __forceinline__ half2v u2h(uint32_t u) {
    union { uint32_t u; half2v h; } c; c.u = u; return c.h;
}
__device__ __forceinline__ uint32_t pk(float lo, float hi) {
    union { uint32_t u; half2v h; } c;
    c.h = __builtin_amdgcn_cvt_pkrtz(lo, hi);
    return c.u;
}
__device__ __forceinline__ f16x8v u4h8(uint4 u) {
    union { uint4 u; f16x8v h; } c; c.u = u; return c.h;
}
#if __has_builtin(__builtin_amdgcn_fdot2)
__device__ __forceinline__ float dot2(uint32_t a, uint32_t b, float c) {
    return __builtin_amdgcn_fdot2(u2h(a), u2h(b), c, false);
}
#else
__device__ __forceinline__ float dot2(uint32_t a, uint32_t b, float c) {
    float d;
    asm("v_dot2_f32_f16 %0, %1, %2, %3" : "=v"(d) : "v"(a), "v"(b), "v"(c));
    return d;
}
#endif

// ---------------------------------------------------------------------------
// DPP helpers: reductions within each 16-lane row (VALU pipe, no LDS traffic)
// ---------------------------------------------------------------------------
template <int CTRL>
__device__ __forceinline__ float dppmov(float v) {
    return __int_as_float(__builtin_amdgcn_update_dpp(
        0, __float_as_int(v), CTRL, 0xF, 0xF, true));
}
__device__ __forceinline__ float grp_sum16(float v) {
    v += dppmov<0xB1>(v);   // quad_perm xor1
    v += dppmov<0x4E>(v);   // quad_perm xor2
    v += dppmov<0x124>(v);  // row_ror:4
    v += dppmov<0x128>(v);  // row_ror:8
    return v;
}
__device__ __forceinline__ float grp_max16(float v) {
    v = fmaxf(v, dppmov<0xB1>(v));
    v = fmaxf(v, dppmov<0x4E>(v));
    v = fmaxf(v, dppmov<0x124>(v));
    v = fmaxf(v, dppmov<0x128>(v));
    return v;
}

// ---------------------------------------------------------------------------
// MFMA f16 tiled GEMM (round-16, verified): C = A*B (+bias), fp32 I/O,
// f16 compute, fp32 accumulate. 64x64 tile, 4 waves, K-step 32.
// ---------------------------------------------------------------------------
__global__ __launch_bounds__(256) void gemm_mfma(
    const float* __restrict__ A, int lda,
    const float* __restrict__ B, int ldb,
    float* __restrict__ C, int ldc,
    int M, int N, int kc, const float* __restrict__ bias)
{
    __shared__ uint32_t AhU[64 * 28];   // [row][k-pair], stride 28 uints
    __shared__ uint32_t BhU[64 * 28];   // [col][k-pair] (transposed)
    const int tid = threadIdx.x;
    const int bm = blockIdx.y * 64;
    const int bn = blockIdx.x * 64;
    const int k0 = blockIdx.z * kc;
    C += (size_t)blockIdx.z * M * N;

    const int lane = tid & 63;
    const int w = tid >> 6;
    const int lr = lane & 15;       // A-row / B-col / D-col within tile
    const int lg = lane >> 4;       // k-group 0..3

    f32x4v acc[4];
#pragma unroll
    for (int nt = 0; nt < 4; ++nt) acc[nt] = (f32x4v)(0.0f);

    const int sar = tid >> 2;              // A stage: row 0..63
    const int sak = (tid & 3) * 8;         // A stage: k offset 0,8,16,24
    const int sbn = (tid & 15) * 4;        // B stage: col 0..60
    const int sbk = (tid >> 4) * 2;        // B stage: k 0..30 (even)

    for (int kt = k0; kt < k0 + kc; kt += 32) {
        float4 a0 = *(const float4*)&A[(size_t)(bm + sar) * lda + kt + sak];
        float4 a1 = *(const float4*)&A[(size_t)(bm + sar) * lda + kt + sak + 4];
        float4 b0 = *(const float4*)&B[(size_t)(kt + sbk) * ldb + bn + sbn];
        float4 b1 = *(const float4*)&B[(size_t)(kt + sbk + 1) * ldb + bn + sbn];
        __syncthreads();   // previous iter's fragment reads complete
        *(uint4*)&AhU[sar * 28 + (tid & 3) * 4] =
            make_uint4(pk(a0.x, a0.y), pk(a0.z, a0.w),
                       pk(a1.x, a1.y), pk(a1.z, a1.w));
        BhU[(sbn + 0) * 28 + (tid >> 4)] = pk(b0.x, b1.x);
        BhU[(sbn + 1) * 28 + (tid >> 4)] = pk(b0.y, b1.y);
        BhU[(sbn + 2) * 28 + (tid >> 4)] = pk(b0.z, b1.z);
        BhU[(sbn + 3) * 28 + (tid >> 4)] = pk(b0.w, b1.w);
        __syncthreads();

        f16x8v af = u4h8(*(const uint4*)&AhU[(16 * w + lr) * 28 + lg * 4]);
#pragma unroll
        for (int nt = 0; nt < 4; ++nt) {
            f16x8v bf = u4h8(*(const uint4*)&BhU[(nt * 16 + lr) * 28 + lg * 4]);
            acc[nt] = __builtin_amdgcn_mfma_f32_16x16x32_f16(af, bf, acc[nt], 0, 0, 0);
        }
    }

#pragma unroll
    for (int nt = 0; nt < 4; ++nt) {
        const int col = bn + nt * 16 + lr;
        const float badd = bias ? bias[col] : 0.0f;
#pragma unroll
        for (int reg = 0; reg < 4; ++reg) {
            const int row = bm + 16 * w + 4 * lg + reg;
            C[(size_t)row * ldc + col] = acc[nt][reg] + badd;
        }
    }
}

// ---------------------------------------------------------------------------
// Fused quarter-token attn, round 17 = round-15 kernel with two chain cuts:
//   (1) NSOLVE 3->2: support settles by sweep 2; final normalization
//       (ensure_sum_one) absorbs residual tau error (4->3 was absmax-neutral)
//   (2) q prefetch: next iteration's 8 q floats load right after scores,
//       hiding global latency under solver+PV (static-indexed qv/qn only)
// Everything else byte-identical (single x2[16], unroll-2, (256,4)).
// WRITE_SIZE == 8192 is the no-scratch tripwire.
// ---------------------------------------------------------------------------
#define QROWS 128
#define NSOLVE 2
#define NBISECT 3
#define NNEWTON 6

__global__ __launch_bounds__(256, 4) void attn_entmax(
    const float* __restrict__ qg, const float* __restrict__ kg,
    const float* __restrict__ vg, float* resg,
    const float* __restrict__ alpha_p)
{
    __shared__ uint32_t ks16[4 * 512];   // [h2][j]  = (k[2h2][j], k[2h2+1][j])
    __shared__ uint32_t vs16[8 * 256];   // [h][j2]  = (v[h][2j2], v[h][2j2+1])
    const int t = blockIdx.x >> 2;
    const int base = (blockIdx.x & 3) * QROWS;
    const int tid = threadIdx.x;

    const float alpha = alpha_p[0];
    const float expo = 1.0f / (alpha - 1.0f);      // = 2 for alpha=1.5 (exact)
    const bool fast = (expo == 2.0f);
    const float scl = (alpha - 1.0f) * 0.04419417382415922f;  // (a-1)/sqrt(512)
    const float hispan = powf(1.0f / 512.0f, alpha - 1.0f);

    const float qmul = fast ? 4.0f * scl : scl;    // fast path: x' = 4x
    const float TGT  = fast ? 16.0f : 1.0f;
    const float loO  = fast ? 4.0f : 1.0f;         // tau >= m - loO
    const float hiO  = (fast ? 4.0f : 1.0f) * hispan;

    {   // ---- stage K (h-pair packed) and V (j-pair packed); q not staged
        const float4* k4g = (const float4*)(kg + (size_t)t * 4096);
        const float4* v4g = (const float4*)(vg + (size_t)t * 4096);
#pragma unroll
        for (int a0 = 0; a0 < 2; ++a0) {
            int idx = tid + 256 * a0;          // 0..511: h2 = idx>>7, j4 = idx&127
            int h2 = idx >> 7, j4 = idx & 127;
            float4 g0 = k4g[(2 * h2) * 128 + j4];
            float4 g1 = k4g[(2 * h2 + 1) * 128 + j4];
            uint4 p4 = make_uint4(pk(g0.x, g1.x), pk(g0.y, g1.y),
                                  pk(g0.z, g1.z), pk(g0.w, g1.w));
            *(uint4*)&ks16[h2 * 512 + j4 * 4] = p4;
        }
#pragma unroll
        for (int a0 = 0; a0 < 4; ++a0) {
            int f = tid + 256 * a0;            // 0..1023: h = f>>7, j4 = f&127
            int h = f >> 7, j4 = f & 127;
            float4 g = v4g[h * 128 + j4];
            uint2 p2 = make_uint2(pk(g.x, g.y), pk(g.z, g.w));
            *(uint2*)&vs16[h * 256 + j4 * 2] = p2;
        }
    }
    __syncthreads();

    const int lane = tid & 63;
    const int w = tid >> 6;        // wave 0..3
    const int sub = lane >> 4;     // 16-lane group 0..3 (one row each)
    const int lx = lane & 15;

    const f32x2 zero2 = bc2(0.0f);
    const f32x2 one2  = bc2(1.0f);
    const f32x2 big2  = bc2(1e30f);

    const float* qt = qg + (size_t)t * 4096 + base;
    const int r0 = w * 4 + sub;    // this group's row within iteration 0

    // q for iteration 0 (broadcast loads within the 16-lane group)
    float qv[8];
#pragma unroll
    for (int h = 0; h < 8; ++h) qv[h] = qt[h * 512 + r0];

    for (int it = 0; it < QROWS / 16; ++it) {
        const int il = it * 16 + r0;            // local row 0..127

        // pack this row's q (scaled) into f16 h-pairs
        uint32_t qp[4];
#pragma unroll
        for (int h2 = 0; h2 < 4; ++h2)
            qp[h2] = pk(qv[2 * h2] * qmul, qv[2 * h2 + 1] * qmul);

        // ---- scores via dot2: lane cols j = lx*4 + 64*u + {0..3}
        f32x2 x2[16];
        f32x2 mv = bc2(-1e30f), sv = zero2;
#pragma unroll 2
        for (int u = 0; u < 8; ++u) {
            float a0 = 0, a1 = 0, a2 = 0, a3 = 0;
#pragma unroll
            for (int h2 = 0; h2 < 4; ++h2) {
                uint4 kk = *(const uint4*)&ks16[h2 * 512 + lx * 4 + 64 * u];
                uint32_t qh = qp[h2];
                a0 = dot2(kk.x, qh, a0);
                a1 = dot2(kk.y, qh, a1);
                a2 = dot2(kk.z, qh, a2);
                a3 = dot2(kk.w, qh, a3);
            }
            f32x2 A = mk2(a0, a1), B = mk2(a2, a3);
            x2[2 * u] = A;
            x2[2 * u + 1] = B;
            mv = max2(mv, max2(A, B));
            sv = sv + A + B;
        }

        // ---- prefetch next iteration's q: latency hides under solver+PV
        if (it + 1 < QROWS / 16) {
#pragma unroll
            for (int h = 0; h < 8; ++h) qv[h] = qt[h * 512 + il + 16];
        }

        float m = grp_max16(fmaxf(mv.x, mv.y));
        const float tlo = m - loO;             // f(tlo) >= TGT always
        const float thi = m - hiO;             // f(thi) <= TGT always

        float tau;
        if (fast) {
            // seed: row mean, clamped into the bracket
            float s1a = grp_sum16(sv.x + sv.y);
            tau = fminf(fmaxf(s1a * (1.0f / 512.0f), tlo), thi);
            // exact active-set solves, packed sweeps
#pragma unroll
            for (int itr = 0; itr < NSOLVE; ++itr) {
                f32x2 tau2 = bc2(tau);
                f32x2 s1A = zero2, s1B = zero2;
                f32x2 s2A = zero2, s2B = zero2;
                f32x2 cA = zero2, cB = zero2;
#pragma unroll
                for (int j = 0; j < 16; j += 2) {
                    f32x2 rA = x2[j] - tau2;
                    f32x2 rB = x2[j + 1] - tau2;
                    f32x2 rpA = max2(rA, zero2);
                    f32x2 rpB = max2(rB, zero2);
                    s1A = s1A + rpA;
                    s1B = s1B + rpB;
                    s2A = rpA * rpA + s2A;
                    s2B = rpB * rpB + s2B;
                    cA = cA + min2(rpA * big2, one2);   // step(rp)
                    cB = cB + min2(rpB * big2, one2);
                }
                f32x2 s1v = s1A + s1B, s2v = s2A + s2B, cv = cA + cB;
                float s1 = grp_sum16(s1v.x + s1v.y);
                float s2 = grp_sum16(s2v.x + s2v.y);
                float nf = grp_sum16(cv.x + cv.y);
                float disc = fmaxf(fmaf(s1, s1, -nf * (s2 - TGT)), 0.0f);
                tau += (s1 - sqrtf(disc)) / fmaxf(nf, 1.0f);
                tau = fminf(fmaxf(tau, tlo), thi);
            }
        } else {
            // generic alpha: bisect + Newton (powf path, scalar components)
            tau = tlo;
            float dm = loO - hiO;
#pragma unroll
            for (int bi = 0; bi < NBISECT; ++bi) {
                dm *= 0.5f;
                float tm = tau + dm;
                float f = 0.0f;
#pragma unroll
                for (int j = 0; j < 16; ++j) {
                    f += __powf(fmaxf(x2[j].x - tm, 0.0f), expo);
                    f += __powf(fmaxf(x2[j].y - tm, 0.0f), expo);
                }
                f = grp_sum16(f);
                if (f >= TGT) tau = tm;
            }
#pragma unroll
            for (int ni = 0; ni < NNEWTON; ++ni) {
                float f = 0.0f, g = 0.0f;
#pragma unroll
                for (int j = 0; j < 16; ++j) {
                    float r0s = fmaxf(x2[j].x - tau, 0.0f);
                    float rp0 = __powf(r0s, expo - 1.0f);
                    g += rp0; f += rp0 * r0s;
                    float r1s = fmaxf(x2[j].y - tau, 0.0f);
                    float rp1 = __powf(r1s, expo - 1.0f);
                    g += rp1; f += rp1 * r1s;
                }
                f = grp_sum16(f);
                g = grp_sum16(g);
                tau += (f - TGT) / fmaxf(expo * g, 1e-30f);
                tau = fminf(fmaxf(tau, tlo), thi);
            }
        }

        // ---- final p; S; pack p to f16 pairs IN PLACE (x2[j].x = pair bits)
        float S;
        if (fast) {
            f32x2 tau2 = bc2(tau);
            f32x2 SA = zero2, SB = zero2;
#pragma unroll
            for (int j = 0; j < 16; j += 2) {
                f32x2 rA = max2(x2[j] - tau2, zero2);
                f32x2 rB = max2(x2[j + 1] - tau2, zero2);
                f32x2 pA = rA * rA;
                f32x2 pB = rB * rB;
                SA = SA + pA;
                SB = SB + pB;
                x2[j].x = __uint_as_float(pk(pA.x, pA.y));
                x2[j + 1].x = __uint_as_float(pk(pB.x, pB.y));
            }
            f32x2 Sv = SA + SB;
            S = Sv.x + Sv.y;
        } else {
            float s0 = 0.0f;
#pragma unroll
            for (int j = 0; j < 16; ++j) {
                float p0 = __powf(fmaxf(x2[j].x - tau, 0.0f), expo);
                float p1 = __powf(fmaxf(x2[j].y - tau, 0.0f), expo);
                s0 += p0 + p1;
                x2[j].x = __uint_as_float(pk(p0, p1));
            }
            S = s0;
        }
        S = grp_sum16(S);
        const float invS = 1.0f / S;

        // ---- res[h,i] = invS * sum_j p[j] v[h,j] via dot2 on j-pairs
#pragma unroll
        for (int h = 0; h < 8; ++h) {
            float aA = 0.0f, aB = 0.0f;
#pragma unroll 2
            for (int u = 0; u < 8; ++u) {
                uint2 vv = *(const uint2*)&vs16[h * 256 + lx * 2 + 32 * u];
                aA = dot2(__float_as_uint(x2[2 * u].x), vv.x, aA);
                aB = dot2(__float_as_uint(x2[2 * u + 1].x), vv.y, aB);
            }
            float a = grp_sum16(aA + aB) * invS;
            if (lx == h) resg[(size_t)t * 4096 + h * 512 + base + il] = a;
        }
    }
}

// ---------------------------------------------------------------------------
__global__ __launch_bounds__(256) void reduce_bias(
    const float* __restrict__ part, const float* __restrict__ bu,
    float* __restrict__ out, int MN, int S)
{
    int i = blockIdx.x * 256 + threadIdx.x;
    if (i >= MN) return;
    float a = bu[i & 511];
#pragma unroll
    for (int s = 0; s < 8; ++s) a += part[(size_t)s * MN + i];
    out[i] = a;
}

// ---------------------------------------------------------------------------
extern "C" void kernel_launch(void* const* d_in, const int* in_sizes, int n_in,
                              void* d_out, int out_size, void* d_ws, size_t ws_size,
                              hipStream_t stream)
{
    const float* x  = (const float*)d_in[0];
    const float* Wq = (const float*)d_in[1];
    const float* bq = (const float*)d_in[2];
    const float* Wk = (const float*)d_in[3];
    const float* bk = (const float*)d_in[4];
    const float* Wv = (const float*)d_in[5];
    const float* bv = (const float*)d_in[6];
    const float* Wu = (const float*)d_in[7];
    const float* bu = (const float*)d_in[8];
    const float* al = (const float*)d_in[9];
    float* out = (float*)d_out;
    float* ws = (float*)d_ws;

    // ws layout (floats): q[2M] | k[2M] | v[2M]
    // res aliases q: each attn block reads q rows only for its own disjoint
    // (t, base..+127) slice; stores at iteration `it` touch rows disjoint
    // from all later reads. Split-K partials alias k (dead after attn).
    float* q = ws;
    float* k = ws + 2097152;
    float* v = ws + 2 * 2097152;
    float* res = q;
    float* part = k;

    dim3 blk(256);

    // QKV projections via MFMA f16 (fp32 accumulate)
    dim3 g1(4096 / 64, 512 / 64, 1);
    gemm_mfma<<<g1, blk, 0, stream>>>(x, 512, Wq, 4096, q, 4096, 512, 4096, 512, bq);
    gemm_mfma<<<g1, blk, 0, stream>>>(x, 512, Wk, 4096, k, 4096, 512, 4096, 512, bk);
    gemm_mfma<<<g1, blk, 0, stream>>>(x, 512, Wv, 4096, v, 4096, 512, 4096, 512, bv);

    // fused scores + alpha-entmax + P*V^T, quarter token per block
    attn_entmax<<<dim3(2048), blk, 0, stream>>>(q, k, v, res, al);

    // out = res @ Wu + bu, split-K=8 via MFMA, then reduce
    dim3 g3(512 / 64, 512 / 64, 8);
    gemm_mfma<<<g3, blk, 0, stream>>>(res, 4096, Wu, 512, part, 512, 512, 512, 512, nullptr);
    reduce_bias<<<dim3(262144 / 256), blk, 0, stream>>>(part, bu, out, 262144, 8);
}

// Round 19
// 202.890 us; speedup vs baseline: 5.2196x; 1.1443x over previous
//
#include <hip/hip_runtime.h>
#include <hip/hip_bf16.h>
#include <stdint.h>

// ---------------------------------------------------------------------------
// Packed 2xfp32 helpers — lower to v_pk_fma_f32 / v_pk_add_f32 / v_pk_max_f32
// ---------------------------------------------------------------------------
typedef float f32x2 __attribute__((ext_vector_type(2)));

__device__ __forceinline__ f32x2 mk2(float a, float b) { f32x2 r; r.x = a; r.y = b; return r; }
__device__ __forceinline__ f32x2 bc2(float a) { f32x2 r; r.x = a; r.y = a; return r; }
__device__ __forceinline__ f32x2 max2(f32x2 a, f32x2 b) {
#if __has_builtin(__builtin_elementwise_max)
    return __builtin_elementwise_max(a, b);
#else
    return mk2(fmaxf(a.x, b.x), fmaxf(a.y, b.y));
#endif
}
__device__ __forceinline__ f32x2 min2(f32x2 a, f32x2 b) {
#if __has_builtin(__builtin_elementwise_min)
    return __builtin_elementwise_min(a, b);
#else
    return mk2(fminf(a.x, b.x), fminf(a.y, b.y));
#endif
}

// ---------------------------------------------------------------------------
// f16 helpers + v_dot2_f32_f16 (attn) and MFMA fragment types (GEMM)
// ---------------------------------------------------------------------------
typedef __fp16 half2v __attribute__((ext_vector_type(2)));
typedef __fp16 f16x8v __attribute__((ext_vector_type(8)));
typedef float f32x4v __attribute__((ext_vector_type(4)));

__device__ __forceinline__ half2v u2h(uint32_t u) {
    union { uint32_t u; half2v h; } c; c.u = u; return c.h;
}
__device__ __forceinline__ uint32_t pk(float lo, float hi) {
    union { uint32_t u; half2v h; } c;
    c.h = __builtin_amdgcn_cvt_pkrtz(lo, hi);
    return c.u;
}
__device__ __forceinline__ f16x8v u4h8(uint4 u) {
    union { uint4 u; f16x8v h; } c; c.u = u; return c.h;
}
#if __has_builtin(__builtin_amdgcn_fdot2)
__device__ __forceinline__ float dot2(uint32_t a, uint32_t b, float c) {
    return __builtin_amdgcn_fdot2(u2h(a), u2h(b), c, false);
}
#else
__device__ __forceinline__ float dot2(uint32_t a, uint32_t b, float c) {
    float d;
    asm("v_dot2_f32_f16 %0, %1, %2, %3" : "=v"(d) : "v"(a), "v"(b), "v"(c));
    return d;
}
#endif

// ---------------------------------------------------------------------------
// DPP helpers: reductions within each 16-lane row (VALU pipe, no LDS traffic)
// ---------------------------------------------------------------------------
template <int CTRL>
__device__ __forceinline__ float dppmov(float v) {
    return __int_as_float(__builtin_amdgcn_update_dpp(
        0, __float_as_int(v), CTRL, 0xF, 0xF, true));
}
__device__ __forceinline__ float grp_sum16(float v) {
    v += dppmov<0xB1>(v);   // quad_perm xor1
    v += dppmov<0x4E>(v);   // quad_perm xor2
    v += dppmov<0x124>(v);  // row_ror:4
    v += dppmov<0x128>(v);  // row_ror:8
    return v;
}
__device__ __forceinline__ float grp_max16(float v) {
    v = fmaxf(v, dppmov<0xB1>(v));
    v = fmaxf(v, dppmov<0x4E>(v));
    v = fmaxf(v, dppmov<0x124>(v));
    v = fmaxf(v, dppmov<0x128>(v));
    return v;
}

// ---------------------------------------------------------------------------
// MFMA f16 GEMM body, double-buffered LDS: ONE barrier per K-step; next
// tile's global loads issue right after the barrier and overlap the MFMAs
// (compiler vmcnt-guards the next LDS write). Hazards: reads of buf[b]
// (iter i) complete before barrier(i+1) [in-order wave + lgkmcnt], and the
// next write of buf[b] (iter i+2) is after barrier(i+1).
// Fragments (gfx94x/95x 16x16x32, verified r16):
//   A: lane l = A[row=l&15][k=(l>>4)*8+0..7]; B: B[k][col=l&15] (transposed
//   in LDS); D: D[row=(l>>4)*4+reg][col=l&15].
// ---------------------------------------------------------------------------
__device__ __forceinline__ void gemm_mfma_body(
    const float* __restrict__ A, int lda,
    const float* __restrict__ B, int ldb,
    float* __restrict__ C, int ldc,
    int kc, int k0, int bm, int bn,
    const float* __restrict__ bias,
    uint32_t* AhU, uint32_t* BhU)   // [2][64*28] each
{
    const int tid = threadIdx.x;
    const int lane = tid & 63;
    const int w = tid >> 6;
    const int lr = lane & 15;
    const int lg = lane >> 4;

    f32x4v acc[4];
#pragma unroll
    for (int nt = 0; nt < 4; ++nt) acc[nt] = (f32x4v)(0.0f);

    const int sar = tid >> 2;              // A stage: row 0..63
    const int sak = (tid & 3) * 8;         // A stage: k offset 0,8,16,24
    const int sbn = (tid & 15) * 4;        // B stage: col 0..60
    const int sbk = (tid >> 4) * 2;        // B stage: k 0..30 (even)

    const int nk = kc >> 5;

    // prologue: load k-step 0 into registers
    float4 a0 = *(const float4*)&A[(size_t)(bm + sar) * lda + k0 + sak];
    float4 a1 = *(const float4*)&A[(size_t)(bm + sar) * lda + k0 + sak + 4];
    float4 b0 = *(const float4*)&B[(size_t)(k0 + sbk) * ldb + bn + sbn];
    float4 b1 = *(const float4*)&B[(size_t)(k0 + sbk + 1) * ldb + bn + sbn];

    for (int ki = 0; ki < nk; ++ki) {
        uint32_t* Ab = AhU + (ki & 1) * (64 * 28);
        uint32_t* Bb = BhU + (ki & 1) * (64 * 28);
        *(uint4*)&Ab[sar * 28 + (tid & 3) * 4] =
            make_uint4(pk(a0.x, a0.y), pk(a0.z, a0.w),
                       pk(a1.x, a1.y), pk(a1.z, a1.w));
        Bb[(sbn + 0) * 28 + (tid >> 4)] = pk(b0.x, b1.x);
        Bb[(sbn + 1) * 28 + (tid >> 4)] = pk(b0.y, b1.y);
        Bb[(sbn + 2) * 28 + (tid >> 4)] = pk(b0.z, b1.z);
        Bb[(sbn + 3) * 28 + (tid >> 4)] = pk(b0.w, b1.w);
        __syncthreads();

        if (ki + 1 < nk) {   // prefetch next tile; overlaps MFMAs below
            const int kt = k0 + (ki + 1) * 32;
            a0 = *(const float4*)&A[(size_t)(bm + sar) * lda + kt + sak];
            a1 = *(const float4*)&A[(size_t)(bm + sar) * lda + kt + sak + 4];
            b0 = *(const float4*)&B[(size_t)(kt + sbk) * ldb + bn + sbn];
            b1 = *(const float4*)&B[(size_t)(kt + sbk + 1) * ldb + bn + sbn];
        }

        f16x8v af = u4h8(*(const uint4*)&Ab[(16 * w + lr) * 28 + lg * 4]);
#pragma unroll
        for (int nt = 0; nt < 4; ++nt) {
            f16x8v bf = u4h8(*(const uint4*)&Bb[(nt * 16 + lr) * 28 + lg * 4]);
            acc[nt] = __builtin_amdgcn_mfma_f32_16x16x32_f16(af, bf, acc[nt], 0, 0, 0);
        }
    }

#pragma unroll
    for (int nt = 0; nt < 4; ++nt) {
        const int col = bn + nt * 16 + lr;
        const float badd = bias ? bias[col] : 0.0f;
#pragma unroll
        for (int reg = 0; reg < 4; ++reg) {
            const int row = bm + 16 * w + 4 * lg + reg;
            C[(size_t)row * ldc + col] = acc[nt][reg] + badd;
        }
    }
}

// QKV fused: blockIdx.z in {0,1,2} selects (W,bias,out); full K=512.
__global__ __launch_bounds__(256) void gemm_qkv(
    const float* __restrict__ x,
    const float* __restrict__ Wq, const float* __restrict__ bq, float* q,
    const float* __restrict__ Wk, const float* __restrict__ bk, float* k,
    const float* __restrict__ Wv, const float* __restrict__ bv, float* v)
{
    __shared__ uint32_t AhU[2 * 64 * 28];
    __shared__ uint32_t BhU[2 * 64 * 28];
    const float* B = Wq; const float* bias = bq; float* C = q;
    if (blockIdx.z == 1) { B = Wk; bias = bk; C = k; }
    if (blockIdx.z == 2) { B = Wv; bias = bv; C = v; }
    gemm_mfma_body(x, 512, B, 4096, C, 4096, 512, 0,
                   blockIdx.y * 64, blockIdx.x * 64, bias, AhU, BhU);
}

// Split-K out-GEMM: blockIdx.z = K-slice, writes partials.
__global__ __launch_bounds__(256) void gemm_out(
    const float* __restrict__ A, const float* __restrict__ Wu,
    float* __restrict__ part)
{
    __shared__ uint32_t AhU[2 * 64 * 28];
    __shared__ uint32_t BhU[2 * 64 * 28];
    float* C = part + (size_t)blockIdx.z * 512 * 512;
    gemm_mfma_body(A, 4096, Wu, 512, C, 512, 512, blockIdx.z * 512,
                   blockIdx.y * 64, blockIdx.x * 64, nullptr, AhU, BhU);
}

// ---------------------------------------------------------------------------
// Fused quarter-token attn, round 18 = round-17 kernel with sweep 2 switched
// from exact active-set to plain Newton (f=s2, f'=-2*s1; monotone from below
// on convex decreasing f) — drops the nf chains + one grp_sum16. Everything
// else byte-identical. WRITE_SIZE == 8192 is the no-scratch tripwire.
// ---------------------------------------------------------------------------
#define QROWS 128
#define NBISECT 3
#define NNEWTON 6

__global__ __launch_bounds__(256, 4) void attn_entmax(
    const float* __restrict__ qg, const float* __restrict__ kg,
    const float* __restrict__ vg, float* resg,
    const float* __restrict__ alpha_p)
{
    __shared__ uint32_t ks16[4 * 512];   // [h2][j]  = (k[2h2][j], k[2h2+1][j])
    __shared__ uint32_t vs16[8 * 256];   // [h][j2]  = (v[h][2j2], v[h][2j2+1])
    const int t = blockIdx.x >> 2;
    const int base = (blockIdx.x & 3) * QROWS;
    const int tid = threadIdx.x;

    const float alpha = alpha_p[0];
    const float expo = 1.0f / (alpha - 1.0f);      // = 2 for alpha=1.5 (exact)
    const bool fast = (expo == 2.0f);
    const float scl = (alpha - 1.0f) * 0.04419417382415922f;  // (a-1)/sqrt(512)
    const float hispan = powf(1.0f / 512.0f, alpha - 1.0f);

    const float qmul = fast ? 4.0f * scl : scl;    // fast path: x' = 4x
    const float TGT  = fast ? 16.0f : 1.0f;
    const float loO  = fast ? 4.0f : 1.0f;         // tau >= m - loO
    const float hiO  = (fast ? 4.0f : 1.0f) * hispan;

    {   // ---- stage K (h-pair packed) and V (j-pair packed); q not staged
        const float4* k4g = (const float4*)(kg + (size_t)t * 4096);
        const float4* v4g = (const float4*)(vg + (size_t)t * 4096);
#pragma unroll
        for (int a0 = 0; a0 < 2; ++a0) {
            int idx = tid + 256 * a0;          // 0..511: h2 = idx>>7, j4 = idx&127
            int h2 = idx >> 7, j4 = idx & 127;
            float4 g0 = k4g[(2 * h2) * 128 + j4];
            float4 g1 = k4g[(2 * h2 + 1) * 128 + j4];
            uint4 p4 = make_uint4(pk(g0.x, g1.x), pk(g0.y, g1.y),
                                  pk(g0.z, g1.z), pk(g0.w, g1.w));
            *(uint4*)&ks16[h2 * 512 + j4 * 4] = p4;
        }
#pragma unroll
        for (int a0 = 0; a0 < 4; ++a0) {
            int f = tid + 256 * a0;            // 0..1023: h = f>>7, j4 = f&127
            int h = f >> 7, j4 = f & 127;
            float4 g = v4g[h * 128 + j4];
            uint2 p2 = make_uint2(pk(g.x, g.y), pk(g.z, g.w));
            *(uint2*)&vs16[h * 256 + j4 * 2] = p2;
        }
    }
    __syncthreads();

    const int lane = tid & 63;
    const int w = tid >> 6;        // wave 0..3
    const int sub = lane >> 4;     // 16-lane group 0..3 (one row each)
    const int lx = lane & 15;

    const f32x2 zero2 = bc2(0.0f);
    const f32x2 one2  = bc2(1.0f);
    const f32x2 big2  = bc2(1e30f);

    const float* qt = qg + (size_t)t * 4096 + base;
    const int r0 = w * 4 + sub;    // this group's row within iteration 0

    // q for iteration 0 (broadcast loads within the 16-lane group)
    float qv[8];
#pragma unroll
    for (int h = 0; h < 8; ++h) qv[h] = qt[h * 512 + r0];

    for (int it = 0; it < QROWS / 16; ++it) {
        const int il = it * 16 + r0;            // local row 0..127

        // pack this row's q (scaled) into f16 h-pairs
        uint32_t qp[4];
#pragma unroll
        for (int h2 = 0; h2 < 4; ++h2)
            qp[h2] = pk(qv[2 * h2] * qmul, qv[2 * h2 + 1] * qmul);

        // ---- scores via dot2: lane cols j = lx*4 + 64*u + {0..3}
        f32x2 x2[16];
        f32x2 mv = bc2(-1e30f), sv = zero2;
#pragma unroll 2
        for (int u = 0; u < 8; ++u) {
            float a0 = 0, a1 = 0, a2 = 0, a3 = 0;
#pragma unroll
            for (int h2 = 0; h2 < 4; ++h2) {
                uint4 kk = *(const uint4*)&ks16[h2 * 512 + lx * 4 + 64 * u];
                uint32_t qh = qp[h2];
                a0 = dot2(kk.x, qh, a0);
                a1 = dot2(kk.y, qh, a1);
                a2 = dot2(kk.z, qh, a2);
                a3 = dot2(kk.w, qh, a3);
            }
            f32x2 A = mk2(a0, a1), B = mk2(a2, a3);
            x2[2 * u] = A;
            x2[2 * u + 1] = B;
            mv = max2(mv, max2(A, B));
            sv = sv + A + B;
        }

        // ---- prefetch next iteration's q: latency hides under solver+PV
        if (it + 1 < QROWS / 16) {
#pragma unroll
            for (int h = 0; h < 8; ++h) qv[h] = qt[h * 512 + il + 16];
        }

        float m = grp_max16(fmaxf(mv.x, mv.y));
        const float tlo = m - loO;             // f(tlo) >= TGT always
        const float thi = m - hiO;             // f(thi) <= TGT always

        float tau;
        if (fast) {
            // seed: row mean, clamped into the bracket
            float s1a = grp_sum16(sv.x + sv.y);
            tau = fminf(fmaxf(s1a * (1.0f / 512.0f), tlo), thi);

            // sweep 1: exact active-set solve (s1, s2, nf)
            {
                f32x2 tau2 = bc2(tau);
                f32x2 s1A = zero2, s1B = zero2;
                f32x2 s2A = zero2, s2B = zero2;
                f32x2 cA = zero2, cB = zero2;
#pragma unroll
                for (int j = 0; j < 16; j += 2) {
                    f32x2 rpA = max2(x2[j] - tau2, zero2);
                    f32x2 rpB = max2(x2[j + 1] - tau2, zero2);
                    s1A = s1A + rpA;
                    s1B = s1B + rpB;
                    s2A = rpA * rpA + s2A;
                    s2B = rpB * rpB + s2B;
                    cA = cA + min2(rpA * big2, one2);
                    cB = cB + min2(rpB * big2, one2);
                }
                f32x2 s1v = s1A + s1B, s2v = s2A + s2B, cv = cA + cB;
                float s1 = grp_sum16(s1v.x + s1v.y);
                float s2 = grp_sum16(s2v.x + s2v.y);
                float nf = grp_sum16(cv.x + cv.y);
                float disc = fmaxf(fmaf(s1, s1, -nf * (s2 - TGT)), 0.0f);
                tau += (s1 - sqrtf(disc)) / fmaxf(nf, 1.0f);
                tau = fminf(fmaxf(tau, tlo), thi);
            }
            // sweep 2: Newton step (s1, s2 only; monotone from below)
            {
                f32x2 tau2 = bc2(tau);
                f32x2 s1A = zero2, s1B = zero2;
                f32x2 s2A = zero2, s2B = zero2;
#pragma unroll
                for (int j = 0; j < 16; j += 2) {
                    f32x2 rpA = max2(x2[j] - tau2, zero2);
                    f32x2 rpB = max2(x2[j + 1] - tau2, zero2);
                    s1A = s1A + rpA;
                    s1B = s1B + rpB;
                    s2A = rpA * rpA + s2A;
                    s2B = rpB * rpB + s2B;
                }
                f32x2 s1v = s1A + s1B, s2v = s2A + s2B;
                float s1 = grp_sum16(s1v.x + s1v.y);
                float s2 = grp_sum16(s2v.x + s2v.y);
                tau += (s2 - TGT) / fmaxf(2.0f * s1, 1e-20f);
                tau = fminf(fmaxf(tau, tlo), thi);
            }
        } else {
            // generic alpha: bisect + Newton (powf path, scalar components)
            tau = tlo;
            float dm = loO - hiO;
#pragma unroll
            for (int bi = 0; bi < NBISECT; ++bi) {
                dm *= 0.5f;
                float tm = tau + dm;
                float f = 0.0f;
#pragma unroll
                for (int j = 0; j < 16; ++j) {
                    f += __powf(fmaxf(x2[j].x - tm, 0.0f), expo);
                    f += __powf(fmaxf(x2[j].y - tm, 0.0f), expo);
                }
                f = grp_sum16(f);
                if (f >= TGT) tau = tm;
            }
#pragma unroll
            for (int ni = 0; ni < NNEWTON; ++ni) {
                float f = 0.0f, g = 0.0f;
#pragma unroll
                for (int j = 0; j < 16; ++j) {
                    float r0s = fmaxf(x2[j].x - tau, 0.0f);
                    float rp0 = __powf(r0s, expo - 1.0f);
                    g += rp0; f += rp0 * r0s;
                    float r1s = fmaxf(x2[j].y - tau, 0.0f);
                    float rp1 = __powf(r1s, expo - 1.0f);
                    g += rp1; f += rp1 * r1s;
                }
                f = grp_sum16(f);
                g = grp_sum16(g);
                tau += (f - TGT) / fmaxf(expo * g, 1e-30f);
                tau = fminf(fmaxf(tau, tlo), thi);
            }
        }

        // ---- final p; S; pack p to f16 pairs IN PLACE (x2[j].x = pair bits)
        float S;
        if (fast) {
            f32x2 tau2 = bc2(tau);
            f32x2 SA = zero2, SB = zero2;
#pragma unroll
            for (int j = 0; j < 16; j += 2) {
                f32x2 rA = max2(x2[j] - tau2, zero2);
                f32x2 rB = max2(x2[j + 1] - tau2, zero2);
                f32x2 pA = rA * rA;
                f32x2 pB = rB * rB;
                SA = SA + pA;
                SB = SB + pB;
                x2[j].x = __uint_as_float(pk(pA.x, pA.y));
                x2[j + 1].x = __uint_as_float(pk(pB.x, pB.y));
            }
            f32x2 Sv = SA + SB;
            S = Sv.x + Sv.y;
        } else {
            float s0 = 0.0f;
#pragma unroll
            for (int j = 0; j < 16; ++j) {
                float p0 = __powf(fmaxf(x2[j].x - tau, 0.0f), expo);
                float p1 = __powf(fmaxf(x2[j].y - tau, 0.0f), expo);
                s0 += p0 + p1;
                x2[j].x = __uint_as_float(pk(p0, p1));
            }
            S = s0;
        }
        S = grp_sum16(S);
        const float invS = 1.0f / S;

        // ---- res[h,i] = invS * sum_j p[j] v[h,j] via dot2 on j-pairs
#pragma unroll
        for (int h = 0; h < 8; ++h) {
            float aA = 0.0f, aB = 0.0f;
#pragma unroll 2
            for (int u = 0; u < 8; ++u) {
                uint2 vv = *(const uint2*)&vs16[h * 256 + lx * 2 + 32 * u];
                aA = dot2(__float_as_uint(x2[2 * u].x), vv.x, aA);
                aB = dot2(__float_as_uint(x2[2 * u + 1].x), vv.y, aB);
            }
            float a = grp_sum16(aA + aB) * invS;
            if (lx == h) resg[(size_t)t * 4096 + h * 512 + base + il] = a;
        }
    }
}

// ---------------------------------------------------------------------------
__global__ __launch_bounds__(256) void reduce_bias(
    const float* __restrict__ part, const float* __restrict__ bu,
    float* __restrict__ out, int MN, int S)
{
    int i = blockIdx.x * 256 + threadIdx.x;
    if (i >= MN) return;
    float a = bu[i & 511];
#pragma unroll
    for (int s = 0; s < 8; ++s) a += part[(size_t)s * MN + i];
    out[i] = a;
}

// ---------------------------------------------------------------------------
extern "C" void kernel_launch(void* const* d_in, const int* in_sizes, int n_in,
                              void* d_out, int out_size, void* d_ws, size_t ws_size,
                              hipStream_t stream)
{
    const float* x  = (const float*)d_in[0];
    const float* Wq = (const float*)d_in[1];
    const float* bq = (const float*)d_in[2];
    const float* Wk = (const float*)d_in[3];
    const float* bk = (const float*)d_in[4];
    const float* Wv = (const float*)d_in[5];
    const float* bv = (const float*)d_in[6];
    const float* Wu = (const float*)d_in[7];
    const float* bu = (const float*)d_in[8];
    const float* al = (const float*)d_in[9];
    float* out = (float*)d_out;
    float* ws = (float*)d_ws;

    // ws layout (floats): q[2M] | k[2M] | v[2M]
    // res aliases q (disjoint per-block row slices, read-before-write per
    // address); split-K partials alias k (dead after attn_entmax).
    float* q = ws;
    float* k = ws + 2097152;
    float* v = ws + 2 * 2097152;
    float* res = q;
    float* part = k;

    dim3 blk(256);

    // QKV projections: one fused dispatch, z selects {q,k,v}
    gemm_qkv<<<dim3(4096 / 64, 512 / 64, 3), blk, 0, stream>>>(
        x, Wq, bq, q, Wk, bk, k, Wv, bv, v);

    // fused scores + alpha-entmax + P*V^T, quarter token per block
    attn_entmax<<<dim3(2048), blk, 0, stream>>>(q, k, v, res, al);

    // out = res @ Wu + bu, split-K=8 via MFMA, then reduce
    gemm_out<<<dim3(512 / 64, 512 / 64, 8), blk, 0, stream>>>(res, Wu, part);
    reduce_bias<<<dim3(262144 / 256), blk, 0, stream>>>(part, bu, out, 262144, 8);
}